// Round 10
// baseline (2814.502 us; speedup 1.0000x reference)
//
#include <hip/hip_runtime.h>

#define NB 4
#define NN 8192
#define NS 2048
#define NK 32
#define NCF 64
#define R2 0.04f

// ws layout in float units
#define WS_FPSIDX 0              // int[NB*NS]           = 8192
#define WS_PACK   8192           // float4[NB*NN]        = 131072 floats
#define WS_GIDX   139264         // int[NB*NS*NK]        = 262144
#define WS_WT0    401408         // 67*64
#define WS_BB0    405696         // 64
#define WS_WT1    405760         // 64*64
#define WS_BB1    409856         // 64
#define WS_WT2    409920         // 64*128
#define WS_BB2    418112         // 128

__device__ __forceinline__ unsigned long long umax64(unsigned long long a,
                                                     unsigned long long b) {
  return a > b ? a : b;   // v_cmp_lt_u64 + cndmask pair
}

template <int CTRL>
__device__ __forceinline__ void dpp_max64(unsigned& kl, unsigned& kh) {
  // 64-bit max ladder step: bound_ctrl=true -> shifted-in lanes see key=0,
  // which never wins in practice (real winning keys are nonzero).
  unsigned nl = (unsigned)__builtin_amdgcn_update_dpp(0, (int)kl, CTRL, 0xf, 0xf, true);
  unsigned nh = (unsigned)__builtin_amdgcn_update_dpp(0, (int)kh, CTRL, 0xf, 0xf, true);
  unsigned long long cur = ((unsigned long long)kh << 32) | kl;
  unsigned long long oth = ((unsigned long long)nh << 32) | nl;
  bool take = oth > cur;
  kl = take ? nl : kl;
  kh = take ? nh : kh;
}

template <int CTRL>
__device__ __forceinline__ int dpp_imin(int x) {
  int t = __builtin_amdgcn_update_dpp(x, x, CTRL, 0xf, 0xf, false);
  return t < x ? t : x;
}
template <int CTRL>
__device__ __forceinline__ int dpp_imax(int x) {
  int t = __builtin_amdgcn_update_dpp(x, x, CTRL, 0xf, 0xf, false);
  return t > x ? t : x;
}
__device__ __forceinline__ int wave_imin_bcast(int x) {
  x = dpp_imin<0x111>(x); x = dpp_imin<0x112>(x); x = dpp_imin<0x114>(x);
  x = dpp_imin<0x118>(x); x = dpp_imin<0x142>(x); x = dpp_imin<0x143>(x);
  return __builtin_amdgcn_readlane(x, 63);
}
__device__ __forceinline__ int wave_imax_bcast(int x) {
  x = dpp_imax<0x111>(x); x = dpp_imax<0x112>(x); x = dpp_imax<0x114>(x);
  x = dpp_imax<0x118>(x); x = dpp_imax<0x142>(x); x = dpp_imax<0x143>(x);
  return __builtin_amdgcn_readlane(x, 63);
}

__device__ __forceinline__ int morton9(int ix, int iy, int iz) {
  auto sp = [](int v) { return (v & 1) | ((v & 2) << 2) | ((v & 4) << 4); };
  return sp(ix) | (sp(iy) << 1) | (sp(iz) << 2);
}

// ---------------------------------------------------------------------------
// FPS: one block per batch, 1024 threads (16 waves), 8 points/thread.
// Exact semantics preserved: dist init 1e10f, far0=0,
// d = ((dx*dx+dy*dy)+dz*dz) with NO fma contraction; dist=min(dist,d);
// argmax first-index tiebreak via u64 keys.
//
// Key: high = f32 bits of dist; low = (8191-idx)<<18 | cell<<9 (idx bits
// dominate cell bits -> tiebreak exact). Winner's Morton cell rides in the
// key, so the per-wave skip test is pure integer cell-gap math with no LDS
// read. Skip iff g2 >= thr, thr > 64*cachedmax*(1+1e-3) (margin covers the
// distance poly's f32 rounding); skipped waves' dist[] untouched -> cached
// key republished -> bit-identical selection.
//
// INVARIANT (fixes R9): wave 0 holds cx/cy/cz == coords(far) at loop top —
// it reloads them AFTER the cross-wave ladder each iteration. Updating
// waves (wid!=0) load the center at the start of their update. This keeps
// the emit (far, coords) paired correctly.
// ---------------------------------------------------------------------------
__global__ __launch_bounds__(1024)
void fps_kernel(const float* __restrict__ xyz, int* __restrict__ fps_idx,
                float* __restrict__ new_xyz)
{
#pragma clang fp contract(off)
  const int b = blockIdx.x;
  const int tid = threadIdx.x;
  const int lane = tid & 63;
  const int wid = tid >> 6;
  const float* __restrict__ P = xyz + (size_t)b * (NN * 3);

  __shared__ float Pl[NN * 3];                 // 96 KB staged coords
  __shared__ unsigned short sidx[NN];          // 16 KB binned orig indices
  __shared__ int hist[512];                    // Morton-cell histogram/offsets
  __shared__ unsigned long long skey[2][16];   // double-buffered wave keys

  // ---- one-time: stage coords, Morton-bin, scatter ----
  {
    const float4* __restrict__ src = (const float4*)P;
    float4* dst = (float4*)Pl;
#pragma unroll
    for (int i = 0; i < 6; ++i) dst[tid + i * 1024] = src[tid + i * 1024];
  }
  if (tid < 512) hist[tid] = 0;
  __syncthreads();

  unsigned short mycell[8];
#pragma unroll
  for (int j = 0; j < 8; ++j) {
    int p = tid + j * 1024;
    float x = Pl[p * 3 + 0], y = Pl[p * 3 + 1], z = Pl[p * 3 + 2];
    int ix = min(7, max(0, (int)(x * 8.0f)));
    int iy = min(7, max(0, (int)(y * 8.0f)));
    int iz = min(7, max(0, (int)(z * 8.0f)));
    int cell = morton9(ix, iy, iz);
    mycell[j] = (unsigned short)cell;
    atomicAdd(&hist[cell], 1);
  }
  __syncthreads();
  if (tid == 0) {   // exclusive prefix (one-time; 512 cells)
    int acc = 0;
    for (int c = 0; c < 512; ++c) { int h = hist[c]; hist[c] = acc; acc += h; }
  }
  __syncthreads();
#pragma unroll
  for (int j = 0; j < 8; ++j) {
    int p = tid + j * 1024;
    int pos = atomicAdd(&hist[mycell[j]], 1);
    sidx[pos] = (unsigned short)p;
  }
  __syncthreads();

  // ---- load my 8 binned points; build constant key-low words; int bbox ----
  float px[8], py[8], pz[8], dist[8];
  unsigned lowc[8];
  int tminx = 99, tmaxx = -1, tminy = 99, tmaxy = -1, tminz = 99, tmaxz = -1;
#pragma unroll
  for (int j = 0; j < 8; ++j) {
    int slot = wid * 512 + j * 64 + lane;
    int p = sidx[slot];
    px[j] = Pl[p * 3 + 0];
    py[j] = Pl[p * 3 + 1];
    pz[j] = Pl[p * 3 + 2];
    dist[j] = 1e10f;
    int ix = min(7, max(0, (int)(px[j] * 8.0f)));
    int iy = min(7, max(0, (int)(py[j] * 8.0f)));
    int iz = min(7, max(0, (int)(pz[j] * 8.0f)));
    lowc[j] = ((unsigned)(8191 - p) << 18) | ((unsigned)morton9(ix, iy, iz) << 9);
    tminx = min(tminx, ix); tmaxx = max(tmaxx, ix);
    tminy = min(tminy, iy); tmaxy = max(tmaxy, iy);
    tminz = min(tminz, iz); tmaxz = max(tmaxz, iz);
  }
  const int wlox = wave_imin_bcast(tminx), whix = wave_imax_bcast(tmaxx);
  const int wloy = wave_imin_bcast(tminy), whiy = wave_imax_bcast(tmaxy);
  const int wloz = wave_imin_bcast(tminz), whiz = wave_imax_bcast(tmaxz);

  float cx = P[0], cy = P[1], cz = P[2];   // first center = point 0
  int far = 0;
  int qcx = 0, qcy = 0, qcz = 0;           // center cell (valid from iter 1)
  int thr = 0x7FFFFFFF;                    // forces update at k=0
  unsigned ckl = 0u, ckh = 0u;             // cached wave key (lane 63 holds it)

  for (int k = 0; k < NS; ++k) {
    if (tid == 0) {
      fps_idx[b * NS + k] = far;
      float* o = new_xyz + ((size_t)b * NS + k) * 3;
      o[0] = cx; o[1] = cy; o[2] = cz;     // invariant: cx == coords(far)
    }
    if (k == NS - 1) break;

    // ---- integer cell-gap skip test (uniform; exact conservative bound)
    int tx = max(wlox - qcx, qcx - whix); int gx = max(tx - 1, 0);
    int ty = max(wloy - qcy, qcy - whiy); int gy = max(ty - 1, 0);
    int tz = max(wloz - qcz, qcz - whiz); int gz = max(tz - 1, 0);
    int g2 = gx * gx + gy * gy + gz * gz;
    bool upd = (g2 < thr);

    if (upd) {
      if (wid != 0) {   // wave 0 already holds coords(far) via the invariant
        const float* cp = Pl + far * 3;
        cx = cp[0]; cy = cp[1]; cz = cp[2];
      }
      // ---- distance update (exact math) + u64 key build
      unsigned long long k8[8];
#pragma unroll
      for (int j = 0; j < 8; ++j) {
        float dx = px[j] - cx;
        float dy = py[j] - cy;
        float dz = pz[j] - cz;
        float d = (dx * dx + dy * dy) + dz * dz;   // plain mul/add, l-to-r
        float t = fminf(dist[j], d);
        dist[j] = t;
        k8[j] = ((unsigned long long)(unsigned)__float_as_int(t) << 32) | lowc[j];
      }
      unsigned long long t0 = umax64(k8[0], k8[1]);
      unsigned long long t1 = umax64(k8[2], k8[3]);
      unsigned long long t2 = umax64(k8[4], k8[5]);
      unsigned long long t3 = umax64(k8[6], k8[7]);
      unsigned long long bk = umax64(umax64(t0, t1), umax64(t2, t3));

      unsigned kl = (unsigned)bk, kh = (unsigned)(bk >> 32);
      dpp_max64<0x111>(kl, kh);
      dpp_max64<0x112>(kl, kh);
      dpp_max64<0x114>(kl, kh);
      dpp_max64<0x118>(kl, kh);
      dpp_max64<0x142>(kl, kh);
      dpp_max64<0x143>(kl, kh);
      ckl = kl; ckh = kh;
      // new wave max dist -> integer threshold: thr > 64*cm*(1+1e-3)
      float cm = __int_as_float(__builtin_amdgcn_readlane((int)kh, 63));
      thr = (int)(cm * 64.064f) + 2;
    }

    const int ws = k & 1;
    if (lane == 63) {
      skey[ws][wid] = ((unsigned long long)ckh << 32) | ckl;
    }
    __syncthreads();

    // ---- cross-wave reduce over 16 u64 keys (conflict-free b64 reads)
    unsigned long long sk = skey[ws][lane & 15];
    unsigned skl = (unsigned)sk, skh = (unsigned)(sk >> 32);
    dpp_max64<0x111>(skl, skh);
    dpp_max64<0x112>(skl, skh);
    dpp_max64<0x114>(skl, skh);
    dpp_max64<0x118>(skl, skh);  // lane15 of each row = block max
    unsigned kl15 = (unsigned)__builtin_amdgcn_readlane((int)skl, 15);
    far = 8191 - (int)(kl15 >> 18);
    int cell = (int)((kl15 >> 9) & 511u);
    qcx = ((cell) & 1) | ((cell >> 2) & 2) | ((cell >> 4) & 4);
    qcy = ((cell >> 1) & 1) | ((cell >> 3) & 2) | ((cell >> 5) & 4);
    qcz = ((cell >> 2) & 1) | ((cell >> 4) & 2) | ((cell >> 6) & 4);

    if (wid == 0) {   // re-establish invariant: cx == coords(new far)
      const float* cp = Pl + far * 3;
      cx = cp[0]; cy = cp[1]; cz = cp[2];
    }
  }
}

// ---------------------------------------------------------------------------
// pack = {x, y, z, (x*x+y*y)+z*z} per point (sq matches jnp.sum(xyz**2,-1))
// ---------------------------------------------------------------------------
__global__ void prep_pack(const float* __restrict__ xyz, float4* __restrict__ pack)
{
#pragma clang fp contract(off)
  int t = blockIdx.x * 256 + threadIdx.x;
  if (t < NB * NN) {
    float x = xyz[t * 3 + 0], y = xyz[t * 3 + 1], z = xyz[t * 3 + 2];
    float4 v; v.x = x; v.y = y; v.z = z; v.w = (x * x + y * y) + z * z;
    pack[t] = v;
  }
}

// ---------------------------------------------------------------------------
// Fold BN into weights, transpose to (c,o), remap layer0 channels so that
// c'=0..63 are features (orig 3..66) and c'=64..66 are rel-xyz (orig 0..2).
// ---------------------------------------------------------------------------
__global__ void prep_w(
    const float* __restrict__ w0, const float* __restrict__ b0,
    const float* __restrict__ g0, const float* __restrict__ be0,
    const float* __restrict__ m0, const float* __restrict__ v0,
    const float* __restrict__ w1, const float* __restrict__ b1,
    const float* __restrict__ g1, const float* __restrict__ be1,
    const float* __restrict__ m1, const float* __restrict__ v1,
    const float* __restrict__ w2, const float* __restrict__ b2,
    const float* __restrict__ g2, const float* __restrict__ be2,
    const float* __restrict__ m2, const float* __restrict__ v2,
    float* __restrict__ wT0, float* __restrict__ bb0,
    float* __restrict__ wT1, float* __restrict__ bb1,
    float* __restrict__ wT2, float* __restrict__ bb2)
{
  int t = blockIdx.x * 256 + threadIdx.x;
  if (t < 4288) {
    int c = t >> 6, o = t & 63;
    int oc = (c < 64) ? (c + 3) : (c - 64);
    float sc = g0[o] * rsqrtf(v0[o] + 1e-5f);
    wT0[t] = w0[o * 67 + oc] * sc;
  } else if (t < 4352) {
    int o = t - 4288;
    float sc = g0[o] * rsqrtf(v0[o] + 1e-5f);
    bb0[o] = (b0[o] - m0[o]) * sc + be0[o];
  } else if (t < 8448) {
    int u = t - 4352;
    int c = u >> 6, o = u & 63;
    float sc = g1[o] * rsqrtf(v1[o] + 1e-5f);
    wT1[u] = w1[o * 64 + c] * sc;
  } else if (t < 8512) {
    int o = t - 8448;
    float sc = g1[o] * rsqrtf(v1[o] + 1e-5f);
    bb1[o] = (b1[o] - m1[o]) * sc + be1[o];
  } else if (t < 16704) {
    int u = t - 8512;
    int c = u >> 7, o = u & 127;
    float sc = g2[o] * rsqrtf(v2[o] + 1e-5f);
    wT2[u] = w2[o * 64 + c] * sc;
  } else if (t < 16832) {
    int o = t - 16704;
    float sc = g2[o] * rsqrtf(v2[o] + 1e-5f);
    bb2[o] = (b2[o] - m2[o]) * sc + be2[o];
  }
}

// ---------------------------------------------------------------------------
// Ball query: one wave per query point. sqr = (sq_q + sq_x) - 2*dot with
// dot as Eigen-style fma chain over (x,y,z). Packed {x,y,z,sq} float4 loads
// (1 dwordx4/point). First 32 in-ball indices ascending; pad with first hit.
// ---------------------------------------------------------------------------
__global__ __launch_bounds__(256)
void ballq_kernel(const float4* __restrict__ pack,
                  const int* __restrict__ fps_idx, int* __restrict__ gidx)
{
#pragma clang fp contract(off)
  const int lane = threadIdx.x & 63;
  const int q = blockIdx.x * 4 + (threadIdx.x >> 6);
  const int b = q >> 11;
  const int s = q & 2047;
  const float4* __restrict__ PK = pack + (size_t)b * NN;
  const int cidx = fps_idx[b * NS + s];
  const float4 c4 = PK[cidx];
  const float cx = c4.x, cy = c4.y, cz = c4.z, csq = c4.w;
  int* __restrict__ g = gidx + (size_t)q * NK;
  int cnt = 0, firstn = 0;
  bool havefirst = false;
  for (int n0 = 0; n0 < NN; n0 += 64) {
    int n = n0 + lane;
    float4 p4 = PK[n];
    float dot = p4.x * cx;         // first gebp step: fma(a0,b0,0) == rn(a0*b0)
    dot = fmaf(p4.y, cy, dot);
    dot = fmaf(p4.z, cz, dot);
    float sqr = (csq + p4.w) - 2.0f * dot;
    bool in_ = (sqr <= R2);
    unsigned long long m = __ballot(in_);
    if (!havefirst && m) { firstn = n0 + __builtin_ctzll(m); havefirst = true; }
    int pos = cnt + __popcll(m & ((1ull << lane) - 1ull));
    if (in_ && pos < NK) g[pos] = n;
    cnt += __popcll(m);
    if (cnt >= NK) break;
  }
  if (cnt < NK && lane < NK - cnt) g[cnt + lane] = firstn;
}

// ---------------------------------------------------------------------------
// Grouped MLP + k-max: one block (256 thr) per query. g staged in LDS,
// weights (BN-folded, (c,o) layout) from global (L2-hot). Activation row
// read as float4 LDS loads (same FMA order: c ascending). ReLU of layer 3
// deferred past the max (relu∘max == max∘relu).
// ---------------------------------------------------------------------------
__global__ __launch_bounds__(256)
void mlp_kernel(const float* __restrict__ xyz, const float* __restrict__ feat,
                const int* __restrict__ gidx, const float* __restrict__ nxyz,
                const float* __restrict__ wT0, const float* __restrict__ bb0,
                const float* __restrict__ wT1, const float* __restrict__ bb1,
                const float* __restrict__ wT2, const float* __restrict__ bb2,
                float* __restrict__ out)
{
  const int q = blockIdx.x;
  const int b = q >> 11;
  const int tid = threadIdx.x;
  __shared__ int sg[32];
  __shared__ float A[32 * 76];    // stride 76 (=19*4): 16B-aligned rows
  __shared__ float Bf[32 * 76];
  __shared__ float Cf[32 * 132];
  if (tid < 32) sg[tid] = gidx[(size_t)q * NK + tid];
  __syncthreads();
  const int k = tid >> 3, j = tid & 7;
  {
    const int p = sg[k];
    const float* fp = feat + ((size_t)b * NN + p) * NCF + j * 8;
    float4 f0 = *(const float4*)fp;
    float4 f1 = *(const float4*)(fp + 4);
    float* a = &A[k * 76 + j * 8];
    *(float4*)a = f0;
    *(float4*)(a + 4) = f1;
    if (j == 0) {
      float cx = nxyz[(size_t)q * 3 + 0];
      float cy = nxyz[(size_t)q * 3 + 1];
      float cz = nxyz[(size_t)q * 3 + 2];
      const float* pp = xyz + ((size_t)b * NN + p) * 3;
      A[k * 76 + 64] = pp[0] - cx;
      A[k * 76 + 65] = pp[1] - cy;
      A[k * 76 + 66] = pp[2] - cz;
    }
  }
  __syncthreads();
  const int o0 = j * 8;
#define FMA8(gv, base)                                                      \
  {                                                                         \
    const float* wr = (base);                                               \
    float4 wa = *(const float4*)wr;                                         \
    float4 wb = *(const float4*)(wr + 4);                                   \
    a0.x = fmaf(gv, wa.x, a0.x); a0.y = fmaf(gv, wa.y, a0.y);               \
    a0.z = fmaf(gv, wa.z, a0.z); a0.w = fmaf(gv, wa.w, a0.w);               \
    a1.x = fmaf(gv, wb.x, a1.x); a1.y = fmaf(gv, wb.y, a1.y);               \
    a1.z = fmaf(gv, wb.z, a1.z); a1.w = fmaf(gv, wb.w, a1.w);               \
  }
  // ---- layer 1: A[k][0..66] -> Bf[k][0..63]
  {
    float4 a0 = *(const float4*)(bb0 + o0);
    float4 a1 = *(const float4*)(bb0 + o0 + 4);
    const float* Ak = &A[k * 76];
    for (int c = 0; c < 64; c += 4) {
      float4 g4 = *(const float4*)(Ak + c);
      FMA8(g4.x, wT0 + (c + 0) * 64 + o0);
      FMA8(g4.y, wT0 + (c + 1) * 64 + o0);
      FMA8(g4.z, wT0 + (c + 2) * 64 + o0);
      FMA8(g4.w, wT0 + (c + 3) * 64 + o0);
    }
    FMA8(Ak[64], wT0 + 64 * 64 + o0);
    FMA8(Ak[65], wT0 + 65 * 64 + o0);
    FMA8(Ak[66], wT0 + 66 * 64 + o0);
    float* o = &Bf[k * 76 + o0];
    o[0] = fmaxf(a0.x, 0.f); o[1] = fmaxf(a0.y, 0.f);
    o[2] = fmaxf(a0.z, 0.f); o[3] = fmaxf(a0.w, 0.f);
    o[4] = fmaxf(a1.x, 0.f); o[5] = fmaxf(a1.y, 0.f);
    o[6] = fmaxf(a1.z, 0.f); o[7] = fmaxf(a1.w, 0.f);
  }
  __syncthreads();
  // ---- layer 2: Bf[k][0..63] -> A[k][0..63]
  {
    float4 a0 = *(const float4*)(bb1 + o0);
    float4 a1 = *(const float4*)(bb1 + o0 + 4);
    const float* Bk = &Bf[k * 76];
    for (int c = 0; c < 64; c += 4) {
      float4 g4 = *(const float4*)(Bk + c);
      FMA8(g4.x, wT1 + (c + 0) * 64 + o0);
      FMA8(g4.y, wT1 + (c + 1) * 64 + o0);
      FMA8(g4.z, wT1 + (c + 2) * 64 + o0);
      FMA8(g4.w, wT1 + (c + 3) * 64 + o0);
    }
    float* o = &A[k * 76 + o0];
    o[0] = fmaxf(a0.x, 0.f); o[1] = fmaxf(a0.y, 0.f);
    o[2] = fmaxf(a0.z, 0.f); o[3] = fmaxf(a0.w, 0.f);
    o[4] = fmaxf(a1.x, 0.f); o[5] = fmaxf(a1.y, 0.f);
    o[6] = fmaxf(a1.z, 0.f); o[7] = fmaxf(a1.w, 0.f);
  }
  __syncthreads();
  // ---- layer 3: A[k][0..63] -> Cf[k][0..127]  (no relu; folded into max)
  {
    const int t0 = j * 16;
    float4 a0 = *(const float4*)(bb2 + t0);
    float4 a1 = *(const float4*)(bb2 + t0 + 4);
    float4 a2 = *(const float4*)(bb2 + t0 + 8);
    float4 a3 = *(const float4*)(bb2 + t0 + 12);
    const float* Ak = &A[k * 76];
#define FMA16(gv, base)                                                     \
    {                                                                       \
      const float* wr = (base);                                             \
      float4 w0v = *(const float4*)wr;                                      \
      float4 w1v = *(const float4*)(wr + 4);                                \
      float4 w2v = *(const float4*)(wr + 8);                                \
      float4 w3v = *(const float4*)(wr + 12);                               \
      a0.x = fmaf(gv, w0v.x, a0.x); a0.y = fmaf(gv, w0v.y, a0.y);           \
      a0.z = fmaf(gv, w0v.z, a0.z); a0.w = fmaf(gv, w0v.w, a0.w);           \
      a1.x = fmaf(gv, w1v.x, a1.x); a1.y = fmaf(gv, w1v.y, a1.y);           \
      a1.z = fmaf(gv, w1v.z, a1.z); a1.w = fmaf(gv, w1v.w, a1.w);           \
      a2.x = fmaf(gv, w2v.x, a2.x); a2.y = fmaf(gv, w2v.y, a2.y);           \
      a2.z = fmaf(gv, w2v.z, a2.z); a2.w = fmaf(gv, w2v.w, a2.w);           \
      a3.x = fmaf(gv, w3v.x, a3.x); a3.y = fmaf(gv, w3v.y, a3.y);           \
      a3.z = fmaf(gv, w3v.z, a3.z); a3.w = fmaf(gv, w3v.w, a3.w);           \
    }
    for (int c = 0; c < 64; c += 4) {
      float4 g4 = *(const float4*)(Ak + c);
      FMA16(g4.x, wT2 + (c + 0) * 128 + t0);
      FMA16(g4.y, wT2 + (c + 1) * 128 + t0);
      FMA16(g4.z, wT2 + (c + 2) * 128 + t0);
      FMA16(g4.w, wT2 + (c + 3) * 128 + t0);
    }
    float* o = &Cf[k * 132 + t0];
    *(float4*)(o + 0) = a0;
    *(float4*)(o + 4) = a1;
    *(float4*)(o + 8) = a2;
    *(float4*)(o + 12) = a3;
  }
  __syncthreads();
  // ---- max over k, relu, store
  if (tid < 128) {
    float m = Cf[tid];
    for (int kk = 1; kk < 32; ++kk) m = fmaxf(m, Cf[kk * 132 + tid]);
    out[(size_t)(NB * NS * 3) + (size_t)q * 128 + tid] = fmaxf(m, 0.0f);
  }
}

extern "C" void kernel_launch(void* const* d_in, const int* in_sizes, int n_in,
                              void* d_out, int out_size, void* d_ws, size_t ws_size,
                              hipStream_t stream)
{
  (void)in_sizes; (void)n_in; (void)out_size; (void)ws_size;
  const float* xyz  = (const float*)d_in[0];
  const float* feat = (const float*)d_in[1];
  const float* w0 = (const float*)d_in[2];
  const float* b0 = (const float*)d_in[3];
  const float* g0 = (const float*)d_in[4];
  const float* be0 = (const float*)d_in[5];
  const float* m0 = (const float*)d_in[6];
  const float* v0 = (const float*)d_in[7];
  const float* w1 = (const float*)d_in[8];
  const float* b1 = (const float*)d_in[9];
  const float* g1 = (const float*)d_in[10];
  const float* be1 = (const float*)d_in[11];
  const float* m1 = (const float*)d_in[12];
  const float* v1 = (const float*)d_in[13];
  const float* w2 = (const float*)d_in[14];
  const float* b2 = (const float*)d_in[15];
  const float* g2 = (const float*)d_in[16];
  const float* be2 = (const float*)d_in[17];
  const float* m2 = (const float*)d_in[18];
  const float* v2 = (const float*)d_in[19];

  float* ws = (float*)d_ws;
  int* fpsi = (int*)(ws + WS_FPSIDX);
  float4* pack = (float4*)(ws + WS_PACK);
  int* gidx = (int*)(ws + WS_GIDX);
  float* wT0 = ws + WS_WT0; float* bb0 = ws + WS_BB0;
  float* wT1 = ws + WS_WT1; float* bb1 = ws + WS_BB1;
  float* wT2 = ws + WS_WT2; float* bb2 = ws + WS_BB2;
  float* nxyz = (float*)d_out;

  hipLaunchKernelGGL(prep_pack, dim3((NB * NN + 255) / 256), dim3(256), 0, stream,
                     xyz, pack);
  hipLaunchKernelGGL(prep_w, dim3(66), dim3(256), 0, stream,
                     w0, b0, g0, be0, m0, v0,
                     w1, b1, g1, be1, m1, v1,
                     w2, b2, g2, be2, m2, v2,
                     wT0, bb0, wT1, bb1, wT2, bb2);
  hipLaunchKernelGGL(fps_kernel, dim3(NB), dim3(1024), 0, stream,
                     xyz, fpsi, nxyz);
  hipLaunchKernelGGL(ballq_kernel, dim3(NB * NS / 4), dim3(256), 0, stream,
                     pack, fpsi, gidx);
  hipLaunchKernelGGL(mlp_kernel, dim3(NB * NS), dim3(256), 0, stream,
                     xyz, feat, gidx, nxyz,
                     wT0, bb0, wT1, bb1, wT2, bb2, (float*)d_out);
}

// Round 11
// 2754.274 us; speedup vs baseline: 1.0219x; 1.0219x over previous
//
#include <hip/hip_runtime.h>

#define NB 4
#define NN 8192
#define NS 2048
#define NK 32
#define NCF 64
#define R2 0.04f

// ws layout in float units
#define WS_FPSIDX 0              // int[NB*NS]           = 8192
#define WS_PACK   8192           // float4[NB*NN]        = 131072 floats
#define WS_GIDX   139264         // int[NB*NS*NK]        = 262144
#define WS_WT0    401408         // 67*64
#define WS_BB0    405696         // 64
#define WS_WT1    405760         // 64*64
#define WS_BB1    409856         // 64
#define WS_WT2    409920         // 64*128
#define WS_BB2    418112         // 128

__device__ __forceinline__ unsigned long long umax64(unsigned long long a,
                                                     unsigned long long b) {
  return a > b ? a : b;   // v_cmp_lt_u64 + cndmask pair
}

template <int CTRL>
__device__ __forceinline__ void dpp_max64(unsigned& kl, unsigned& kh) {
  // 64-bit max ladder step: bound_ctrl=true -> shifted-in lanes see key=0,
  // which never wins (real winning keys are nonzero).
  unsigned nl = (unsigned)__builtin_amdgcn_update_dpp(0, (int)kl, CTRL, 0xf, 0xf, true);
  unsigned nh = (unsigned)__builtin_amdgcn_update_dpp(0, (int)kh, CTRL, 0xf, 0xf, true);
  unsigned long long cur = ((unsigned long long)kh << 32) | kl;
  unsigned long long oth = ((unsigned long long)nh << 32) | nl;
  bool take = oth > cur;
  kl = take ? nl : kl;
  kh = take ? nh : kh;
}

template <int CTRL>
__device__ __forceinline__ void dpp_max64x2(unsigned& al, unsigned& ah,
                                            unsigned& bl, unsigned& bh) {
  // two independent 64-bit max chains, interleaved (per-half wave maxima)
  unsigned nal = (unsigned)__builtin_amdgcn_update_dpp(0, (int)al, CTRL, 0xf, 0xf, true);
  unsigned nah = (unsigned)__builtin_amdgcn_update_dpp(0, (int)ah, CTRL, 0xf, 0xf, true);
  unsigned nbl = (unsigned)__builtin_amdgcn_update_dpp(0, (int)bl, CTRL, 0xf, 0xf, true);
  unsigned nbh = (unsigned)__builtin_amdgcn_update_dpp(0, (int)bh, CTRL, 0xf, 0xf, true);
  unsigned long long ca = ((unsigned long long)ah << 32) | al;
  unsigned long long oa = ((unsigned long long)nah << 32) | nal;
  bool ta = oa > ca;
  al = ta ? nal : al; ah = ta ? nah : ah;
  unsigned long long cb = ((unsigned long long)bh << 32) | bl;
  unsigned long long ob = ((unsigned long long)nbh << 32) | nbl;
  bool tb = ob > cb;
  bl = tb ? nbl : bl; bh = tb ? nbh : bh;
}

template <int CTRL>
__device__ __forceinline__ float dpp_fmin2(float x) {
  int t = __builtin_amdgcn_update_dpp(__float_as_int(x), __float_as_int(x),
                                      CTRL, 0xf, 0xf, false);
  return fminf(x, __int_as_float(t));
}
template <int CTRL>
__device__ __forceinline__ float dpp_fmax2(float x) {
  int t = __builtin_amdgcn_update_dpp(__float_as_int(x), __float_as_int(x),
                                      CTRL, 0xf, 0xf, false);
  return fmaxf(x, __int_as_float(t));
}
__device__ __forceinline__ float wave_min_bcast(float x) {
  x = dpp_fmin2<0x111>(x); x = dpp_fmin2<0x112>(x); x = dpp_fmin2<0x114>(x);
  x = dpp_fmin2<0x118>(x); x = dpp_fmin2<0x142>(x); x = dpp_fmin2<0x143>(x);
  return __int_as_float(__builtin_amdgcn_readlane(__float_as_int(x), 63));
}
__device__ __forceinline__ float wave_max_bcast(float x) {
  x = dpp_fmax2<0x111>(x); x = dpp_fmax2<0x112>(x); x = dpp_fmax2<0x114>(x);
  x = dpp_fmax2<0x118>(x); x = dpp_fmax2<0x142>(x); x = dpp_fmax2<0x143>(x);
  return __int_as_float(__builtin_amdgcn_readlane(__float_as_int(x), 63));
}

__device__ __forceinline__ int morton9(int ix, int iy, int iz) {
  auto sp = [](int v) { return (v & 1) | ((v & 2) << 2) | ((v & 4) << 4); };
  return sp(ix) | (sp(iy) << 1) | (sp(iz) << 2);
}

// ---------------------------------------------------------------------------
// FPS: one block per batch, 1024 threads (16 waves), 8 points/thread.
// Exact semantics preserved: dist init 1e10f, far0=0,
// d = ((dx*dx+dy*dy)+dz*dz) with NO fma contraction; dist=min(dist,d);
// argmax first-index tiebreak via u64 keys (distbits<<32 | ~idx).
//
// R8 structure (exact float bbox pruning, post-ladder unconditional center
// read) + per-HALF pruning: each wave's 512 Morton-run points split into
// two 256-pt halves, each with its own exact float bbox and cached wave
// key. A half skips iff lb_half^2 * 0.999 >= cmax (wave's overall cached
// max >= that half's max -> its fmin pass is provably a no-op). Cached
// per-half keys republished on skip -> selection bit-identical.
// ---------------------------------------------------------------------------
__global__ __launch_bounds__(1024)
void fps_kernel(const float* __restrict__ xyz, int* __restrict__ fps_idx,
                float* __restrict__ new_xyz)
{
#pragma clang fp contract(off)
  const int b = blockIdx.x;
  const int tid = threadIdx.x;
  const int lane = tid & 63;
  const int wid = tid >> 6;
  const float* __restrict__ P = xyz + (size_t)b * (NN * 3);

  __shared__ float Pl[NN * 3];                 // 96 KB staged coords
  __shared__ unsigned short sidx[NN];          // 16 KB binned orig indices
  __shared__ int hist[512];                    // Morton-cell histogram/offsets
  __shared__ unsigned long long skey[2][16];   // double-buffered wave keys

  // ---- one-time: stage coords, Morton-bin, scatter ----
  {
    const float4* __restrict__ src = (const float4*)P;
    float4* dst = (float4*)Pl;
#pragma unroll
    for (int i = 0; i < 6; ++i) dst[tid + i * 1024] = src[tid + i * 1024];
  }
  if (tid < 512) hist[tid] = 0;
  __syncthreads();

  unsigned short mycell[8];
#pragma unroll
  for (int j = 0; j < 8; ++j) {
    int p = tid + j * 1024;
    float x = Pl[p * 3 + 0], y = Pl[p * 3 + 1], z = Pl[p * 3 + 2];
    int ix = min(7, max(0, (int)(x * 8.0f)));
    int iy = min(7, max(0, (int)(y * 8.0f)));
    int iz = min(7, max(0, (int)(z * 8.0f)));
    int cell = morton9(ix, iy, iz);
    mycell[j] = (unsigned short)cell;
    atomicAdd(&hist[cell], 1);
  }
  __syncthreads();
  if (tid == 0) {   // exclusive prefix (one-time; 512 cells)
    int acc = 0;
    for (int c = 0; c < 512; ++c) { int h = hist[c]; hist[c] = acc; acc += h; }
  }
  __syncthreads();
#pragma unroll
  for (int j = 0; j < 8; ++j) {
    int p = tid + j * 1024;
    int pos = atomicAdd(&hist[mycell[j]], 1);
    sidx[pos] = (unsigned short)p;
  }
  __syncthreads();

  // ---- load my 8 binned points + keys; halves A=j0..3, B=j4..7 ----
  float px[8], py[8], pz[8], dist[8];
  unsigned klc[8];
#pragma unroll
  for (int j = 0; j < 8; ++j) {
    int slot = wid * 512 + j * 64 + lane;
    int p = sidx[slot];
    px[j] = Pl[p * 3 + 0];
    py[j] = Pl[p * 3 + 1];
    pz[j] = Pl[p * 3 + 2];
    dist[j] = 1e10f;
    klc[j] = 0xFFFFFFFFu - (unsigned)p;   // ~orig idx: bigger == smaller index
  }
  // ---- per-half exact float bboxes (broadcast scalars) ----
  float mnxA = fminf(fminf(px[0], px[1]), fminf(px[2], px[3]));
  float mxxA = fmaxf(fmaxf(px[0], px[1]), fmaxf(px[2], px[3]));
  float mnyA = fminf(fminf(py[0], py[1]), fminf(py[2], py[3]));
  float mxyA = fmaxf(fmaxf(py[0], py[1]), fmaxf(py[2], py[3]));
  float mnzA = fminf(fminf(pz[0], pz[1]), fminf(pz[2], pz[3]));
  float mxzA = fmaxf(fmaxf(pz[0], pz[1]), fmaxf(pz[2], pz[3]));
  float mnxB = fminf(fminf(px[4], px[5]), fminf(px[6], px[7]));
  float mxxB = fmaxf(fmaxf(px[4], px[5]), fmaxf(px[6], px[7]));
  float mnyB = fminf(fminf(py[4], py[5]), fminf(py[6], py[7]));
  float mxyB = fmaxf(fmaxf(py[4], py[5]), fmaxf(py[6], py[7]));
  float mnzB = fminf(fminf(pz[4], pz[5]), fminf(pz[6], pz[7]));
  float mxzB = fmaxf(fmaxf(pz[4], pz[5]), fmaxf(pz[6], pz[7]));
  const float blxA = wave_min_bcast(mnxA), bhxA = wave_max_bcast(mxxA);
  const float blyA = wave_min_bcast(mnyA), bhyA = wave_max_bcast(mxyA);
  const float blzA = wave_min_bcast(mnzA), bhzA = wave_max_bcast(mxzA);
  const float blxB = wave_min_bcast(mnxB), bhxB = wave_max_bcast(mxxB);
  const float blyB = wave_min_bcast(mnyB), bhyB = wave_max_bcast(mxyB);
  const float blzB = wave_min_bcast(mnzB), bhzB = wave_max_bcast(mxzB);

  float cx = P[0], cy = P[1], cz = P[2];   // first center = point 0
  int far = 0;
  unsigned ckAl = 0u, ckAh = 0u, ckBl = 0u, ckBh = 0u;  // cached half keys (lane63)
  float cmax = 1e10f;                       // wave overall cached max (forces k=0)

#define UPD_HALF(J0, OUT)                                                     \
  {                                                                           \
    unsigned long long kk0, kk1, kk2, kk3;                                    \
    {                                                                         \
      float dx = px[J0 + 0] - cx, dy = py[J0 + 0] - cy, dz = pz[J0 + 0] - cz; \
      float d = (dx * dx + dy * dy) + dz * dz;                                \
      float t = fminf(dist[J0 + 0], d); dist[J0 + 0] = t;                     \
      kk0 = ((unsigned long long)(unsigned)__float_as_int(t) << 32) | klc[J0 + 0]; \
    }                                                                         \
    {                                                                         \
      float dx = px[J0 + 1] - cx, dy = py[J0 + 1] - cy, dz = pz[J0 + 1] - cz; \
      float d = (dx * dx + dy * dy) + dz * dz;                                \
      float t = fminf(dist[J0 + 1], d); dist[J0 + 1] = t;                     \
      kk1 = ((unsigned long long)(unsigned)__float_as_int(t) << 32) | klc[J0 + 1]; \
    }                                                                         \
    {                                                                         \
      float dx = px[J0 + 2] - cx, dy = py[J0 + 2] - cy, dz = pz[J0 + 2] - cz; \
      float d = (dx * dx + dy * dy) + dz * dz;                                \
      float t = fminf(dist[J0 + 2], d); dist[J0 + 2] = t;                     \
      kk2 = ((unsigned long long)(unsigned)__float_as_int(t) << 32) | klc[J0 + 2]; \
    }                                                                         \
    {                                                                         \
      float dx = px[J0 + 3] - cx, dy = py[J0 + 3] - cy, dz = pz[J0 + 3] - cz; \
      float d = (dx * dx + dy * dy) + dz * dz;                                \
      float t = fminf(dist[J0 + 3], d); dist[J0 + 3] = t;                     \
      kk3 = ((unsigned long long)(unsigned)__float_as_int(t) << 32) | klc[J0 + 3]; \
    }                                                                         \
    OUT = umax64(umax64(kk0, kk1), umax64(kk2, kk3));                         \
  }

  for (int k = 0; k < NS; ++k) {
    if (tid == 0) {
      fps_idx[b * NS + k] = far;
      float* o = new_xyz + ((size_t)b * NS + k) * 3;
      o[0] = cx; o[1] = cy; o[2] = cz;     // invariant: cx == coords(far)
    }
    if (k == NS - 1) break;

    // ---- per-half exact float bbox skip tests (wave-uniform)
    float dlxA = fmaxf(fmaxf(blxA - cx, cx - bhxA), 0.0f);
    float dlyA = fmaxf(fmaxf(blyA - cy, cy - bhyA), 0.0f);
    float dlzA = fmaxf(fmaxf(blzA - cz, cz - bhzA), 0.0f);
    float lbA = dlxA * dlxA + dlyA * dlyA + dlzA * dlzA;
    float dlxB = fmaxf(fmaxf(blxB - cx, cx - bhxB), 0.0f);
    float dlyB = fmaxf(fmaxf(blyB - cy, cy - bhyB), 0.0f);
    float dlzB = fmaxf(fmaxf(blzB - cz, cz - bhzB), 0.0f);
    float lbB = dlxB * dlxB + dlyB * dlyB + dlzB * dlzB;
    int uA = __builtin_amdgcn_readfirstlane((int)!(lbA * 0.999f >= cmax));
    int uB = __builtin_amdgcn_readfirstlane((int)!(lbB * 0.999f >= cmax));

    if (uA && uB) {
      unsigned long long hA, hB;
      UPD_HALF(0, hA);
      UPD_HALF(4, hB);
      unsigned al = (unsigned)hA, ah = (unsigned)(hA >> 32);
      unsigned bl = (unsigned)hB, bh = (unsigned)(hB >> 32);
      dpp_max64x2<0x111>(al, ah, bl, bh);
      dpp_max64x2<0x112>(al, ah, bl, bh);
      dpp_max64x2<0x114>(al, ah, bl, bh);
      dpp_max64x2<0x118>(al, ah, bl, bh);
      dpp_max64x2<0x142>(al, ah, bl, bh);
      dpp_max64x2<0x143>(al, ah, bl, bh);
      ckAl = al; ckAh = ah; ckBl = bl; ckBh = bh;
    } else if (uA) {
      unsigned long long hA;
      UPD_HALF(0, hA);
      unsigned al = (unsigned)hA, ah = (unsigned)(hA >> 32);
      dpp_max64<0x111>(al, ah);
      dpp_max64<0x112>(al, ah);
      dpp_max64<0x114>(al, ah);
      dpp_max64<0x118>(al, ah);
      dpp_max64<0x142>(al, ah);
      dpp_max64<0x143>(al, ah);
      ckAl = al; ckAh = ah;
    } else if (uB) {
      unsigned long long hB;
      UPD_HALF(4, hB);
      unsigned bl = (unsigned)hB, bh = (unsigned)(hB >> 32);
      dpp_max64<0x111>(bl, bh);
      dpp_max64<0x112>(bl, bh);
      dpp_max64<0x114>(bl, bh);
      dpp_max64<0x118>(bl, bh);
      dpp_max64<0x142>(bl, bh);
      dpp_max64<0x143>(bl, bh);
      ckBl = bl; ckBh = bh;
    }

    unsigned long long comb =
        umax64(((unsigned long long)ckAh << 32) | ckAl,
               ((unsigned long long)ckBh << 32) | ckBl);
    if (uA || uB) {   // refresh wave overall cached max (uniform branch)
      cmax = __int_as_float(
          __builtin_amdgcn_readlane((int)(unsigned)(comb >> 32), 63));
    }

    const int ws = k & 1;
    if (lane == 63) skey[ws][wid] = comb;
    __syncthreads();

    // ---- cross-wave reduce over 16 u64 keys (conflict-free b64 reads)
    unsigned long long sk = skey[ws][lane & 15];
    unsigned skl = (unsigned)sk, skh = (unsigned)(sk >> 32);
    dpp_max64<0x111>(skl, skh);
    dpp_max64<0x112>(skl, skh);
    dpp_max64<0x114>(skl, skh);
    dpp_max64<0x118>(skl, skh);  // lane15 of each row = block max
    unsigned kl15 = (unsigned)__builtin_amdgcn_readlane((int)skl, 15);
    far = (int)(0xFFFFFFFFu - kl15);

    // ---- center coords: one same-address broadcast LDS read (all waves)
    const float* cp = Pl + far * 3;
    cx = cp[0]; cy = cp[1]; cz = cp[2];
  }
#undef UPD_HALF
}

// ---------------------------------------------------------------------------
// pack = {x, y, z, (x*x+y*y)+z*z} per point (sq matches jnp.sum(xyz**2,-1))
// ---------------------------------------------------------------------------
__global__ void prep_pack(const float* __restrict__ xyz, float4* __restrict__ pack)
{
#pragma clang fp contract(off)
  int t = blockIdx.x * 256 + threadIdx.x;
  if (t < NB * NN) {
    float x = xyz[t * 3 + 0], y = xyz[t * 3 + 1], z = xyz[t * 3 + 2];
    float4 v; v.x = x; v.y = y; v.z = z; v.w = (x * x + y * y) + z * z;
    pack[t] = v;
  }
}

// ---------------------------------------------------------------------------
// Fold BN into weights, transpose to (c,o), remap layer0 channels so that
// c'=0..63 are features (orig 3..66) and c'=64..66 are rel-xyz (orig 0..2).
// ---------------------------------------------------------------------------
__global__ void prep_w(
    const float* __restrict__ w0, const float* __restrict__ b0,
    const float* __restrict__ g0, const float* __restrict__ be0,
    const float* __restrict__ m0, const float* __restrict__ v0,
    const float* __restrict__ w1, const float* __restrict__ b1,
    const float* __restrict__ g1, const float* __restrict__ be1,
    const float* __restrict__ m1, const float* __restrict__ v1,
    const float* __restrict__ w2, const float* __restrict__ b2,
    const float* __restrict__ g2, const float* __restrict__ be2,
    const float* __restrict__ m2, const float* __restrict__ v2,
    float* __restrict__ wT0, float* __restrict__ bb0,
    float* __restrict__ wT1, float* __restrict__ bb1,
    float* __restrict__ wT2, float* __restrict__ bb2)
{
  int t = blockIdx.x * 256 + threadIdx.x;
  if (t < 4288) {
    int c = t >> 6, o = t & 63;
    int oc = (c < 64) ? (c + 3) : (c - 64);
    float sc = g0[o] * rsqrtf(v0[o] + 1e-5f);
    wT0[t] = w0[o * 67 + oc] * sc;
  } else if (t < 4352) {
    int o = t - 4288;
    float sc = g0[o] * rsqrtf(v0[o] + 1e-5f);
    bb0[o] = (b0[o] - m0[o]) * sc + be0[o];
  } else if (t < 8448) {
    int u = t - 4352;
    int c = u >> 6, o = u & 63;
    float sc = g1[o] * rsqrtf(v1[o] + 1e-5f);
    wT1[u] = w1[o * 64 + c] * sc;
  } else if (t < 8512) {
    int o = t - 8448;
    float sc = g1[o] * rsqrtf(v1[o] + 1e-5f);
    bb1[o] = (b1[o] - m1[o]) * sc + be1[o];
  } else if (t < 16704) {
    int u = t - 8512;
    int c = u >> 7, o = u & 127;
    float sc = g2[o] * rsqrtf(v2[o] + 1e-5f);
    wT2[u] = w2[o * 64 + c] * sc;
  } else if (t < 16832) {
    int o = t - 16704;
    float sc = g2[o] * rsqrtf(v2[o] + 1e-5f);
    bb2[o] = (b2[o] - m2[o]) * sc + be2[o];
  }
}

// ---------------------------------------------------------------------------
// Ball query: one wave per query point. sqr = (sq_q + sq_x) - 2*dot with
// dot as Eigen-style fma chain over (x,y,z). Packed {x,y,z,sq} float4 loads
// (1 dwordx4/point). First 32 in-ball indices ascending; pad with first hit.
// ---------------------------------------------------------------------------
__global__ __launch_bounds__(256)
void ballq_kernel(const float4* __restrict__ pack,
                  const int* __restrict__ fps_idx, int* __restrict__ gidx)
{
#pragma clang fp contract(off)
  const int lane = threadIdx.x & 63;
  const int q = blockIdx.x * 4 + (threadIdx.x >> 6);
  const int b = q >> 11;
  const int s = q & 2047;
  const float4* __restrict__ PK = pack + (size_t)b * NN;
  const int cidx = fps_idx[b * NS + s];
  const float4 c4 = PK[cidx];
  const float cx = c4.x, cy = c4.y, cz = c4.z, csq = c4.w;
  int* __restrict__ g = gidx + (size_t)q * NK;
  int cnt = 0, firstn = 0;
  bool havefirst = false;
  for (int n0 = 0; n0 < NN; n0 += 64) {
    int n = n0 + lane;
    float4 p4 = PK[n];
    float dot = p4.x * cx;         // first gebp step: fma(a0,b0,0) == rn(a0*b0)
    dot = fmaf(p4.y, cy, dot);
    dot = fmaf(p4.z, cz, dot);
    float sqr = (csq + p4.w) - 2.0f * dot;
    bool in_ = (sqr <= R2);
    unsigned long long m = __ballot(in_);
    if (!havefirst && m) { firstn = n0 + __builtin_ctzll(m); havefirst = true; }
    int pos = cnt + __popcll(m & ((1ull << lane) - 1ull));
    if (in_ && pos < NK) g[pos] = n;
    cnt += __popcll(m);
    if (cnt >= NK) break;
  }
  if (cnt < NK && lane < NK - cnt) g[cnt + lane] = firstn;
}

// ---------------------------------------------------------------------------
// Grouped MLP + k-max: one block (256 thr) per query. g staged in LDS,
// weights (BN-folded, (c,o) layout) from global (L2-hot). Activation row
// read as float4 LDS loads (same FMA order: c ascending). ReLU of layer 3
// deferred past the max (relu∘max == max∘relu).
// ---------------------------------------------------------------------------
__global__ __launch_bounds__(256)
void mlp_kernel(const float* __restrict__ xyz, const float* __restrict__ feat,
                const int* __restrict__ gidx, const float* __restrict__ nxyz,
                const float* __restrict__ wT0, const float* __restrict__ bb0,
                const float* __restrict__ wT1, const float* __restrict__ bb1,
                const float* __restrict__ wT2, const float* __restrict__ bb2,
                float* __restrict__ out)
{
  const int q = blockIdx.x;
  const int b = q >> 11;
  const int tid = threadIdx.x;
  __shared__ int sg[32];
  __shared__ float A[32 * 76];    // stride 76 (=19*4): 16B-aligned rows
  __shared__ float Bf[32 * 76];
  __shared__ float Cf[32 * 132];
  if (tid < 32) sg[tid] = gidx[(size_t)q * NK + tid];
  __syncthreads();
  const int k = tid >> 3, j = tid & 7;
  {
    const int p = sg[k];
    const float* fp = feat + ((size_t)b * NN + p) * NCF + j * 8;
    float4 f0 = *(const float4*)fp;
    float4 f1 = *(const float4*)(fp + 4);
    float* a = &A[k * 76 + j * 8];
    *(float4*)a = f0;
    *(float4*)(a + 4) = f1;
    if (j == 0) {
      float cx = nxyz[(size_t)q * 3 + 0];
      float cy = nxyz[(size_t)q * 3 + 1];
      float cz = nxyz[(size_t)q * 3 + 2];
      const float* pp = xyz + ((size_t)b * NN + p) * 3;
      A[k * 76 + 64] = pp[0] - cx;
      A[k * 76 + 65] = pp[1] - cy;
      A[k * 76 + 66] = pp[2] - cz;
    }
  }
  __syncthreads();
  const int o0 = j * 8;
#define FMA8(gv, base)                                                      \
  {                                                                         \
    const float* wr = (base);                                               \
    float4 wa = *(const float4*)wr;                                         \
    float4 wb = *(const float4*)(wr + 4);                                   \
    a0.x = fmaf(gv, wa.x, a0.x); a0.y = fmaf(gv, wa.y, a0.y);               \
    a0.z = fmaf(gv, wa.z, a0.z); a0.w = fmaf(gv, wa.w, a0.w);               \
    a1.x = fmaf(gv, wb.x, a1.x); a1.y = fmaf(gv, wb.y, a1.y);               \
    a1.z = fmaf(gv, wb.z, a1.z); a1.w = fmaf(gv, wb.w, a1.w);               \
  }
  // ---- layer 1: A[k][0..66] -> Bf[k][0..63]
  {
    float4 a0 = *(const float4*)(bb0 + o0);
    float4 a1 = *(const float4*)(bb0 + o0 + 4);
    const float* Ak = &A[k * 76];
    for (int c = 0; c < 64; c += 4) {
      float4 g4 = *(const float4*)(Ak + c);
      FMA8(g4.x, wT0 + (c + 0) * 64 + o0);
      FMA8(g4.y, wT0 + (c + 1) * 64 + o0);
      FMA8(g4.z, wT0 + (c + 2) * 64 + o0);
      FMA8(g4.w, wT0 + (c + 3) * 64 + o0);
    }
    FMA8(Ak[64], wT0 + 64 * 64 + o0);
    FMA8(Ak[65], wT0 + 65 * 64 + o0);
    FMA8(Ak[66], wT0 + 66 * 64 + o0);
    float* o = &Bf[k * 76 + o0];
    o[0] = fmaxf(a0.x, 0.f); o[1] = fmaxf(a0.y, 0.f);
    o[2] = fmaxf(a0.z, 0.f); o[3] = fmaxf(a0.w, 0.f);
    o[4] = fmaxf(a1.x, 0.f); o[5] = fmaxf(a1.y, 0.f);
    o[6] = fmaxf(a1.z, 0.f); o[7] = fmaxf(a1.w, 0.f);
  }
  __syncthreads();
  // ---- layer 2: Bf[k][0..63] -> A[k][0..63]
  {
    float4 a0 = *(const float4*)(bb1 + o0);
    float4 a1 = *(const float4*)(bb1 + o0 + 4);
    const float* Bk = &Bf[k * 76];
    for (int c = 0; c < 64; c += 4) {
      float4 g4 = *(const float4*)(Bk + c);
      FMA8(g4.x, wT1 + (c + 0) * 64 + o0);
      FMA8(g4.y, wT1 + (c + 1) * 64 + o0);
      FMA8(g4.z, wT1 + (c + 2) * 64 + o0);
      FMA8(g4.w, wT1 + (c + 3) * 64 + o0);
    }
    float* o = &A[k * 76 + o0];
    o[0] = fmaxf(a0.x, 0.f); o[1] = fmaxf(a0.y, 0.f);
    o[2] = fmaxf(a0.z, 0.f); o[3] = fmaxf(a0.w, 0.f);
    o[4] = fmaxf(a1.x, 0.f); o[5] = fmaxf(a1.y, 0.f);
    o[6] = fmaxf(a1.z, 0.f); o[7] = fmaxf(a1.w, 0.f);
  }
  __syncthreads();
  // ---- layer 3: A[k][0..63] -> Cf[k][0..127]  (no relu; folded into max)
  {
    const int t0 = j * 16;
    float4 a0 = *(const float4*)(bb2 + t0);
    float4 a1 = *(const float4*)(bb2 + t0 + 4);
    float4 a2 = *(const float4*)(bb2 + t0 + 8);
    float4 a3 = *(const float4*)(bb2 + t0 + 12);
    const float* Ak = &A[k * 76];
#define FMA16(gv, base)                                                     \
    {                                                                       \
      const float* wr = (base);                                             \
      float4 w0v = *(const float4*)wr;                                      \
      float4 w1v = *(const float4*)(wr + 4);                                \
      float4 w2v = *(const float4*)(wr + 8);                                \
      float4 w3v = *(const float4*)(wr + 12);                               \
      a0.x = fmaf(gv, w0v.x, a0.x); a0.y = fmaf(gv, w0v.y, a0.y);           \
      a0.z = fmaf(gv, w0v.z, a0.z); a0.w = fmaf(gv, w0v.w, a0.w);           \
      a1.x = fmaf(gv, w1v.x, a1.x); a1.y = fmaf(gv, w1v.y, a1.y);           \
      a1.z = fmaf(gv, w1v.z, a1.z); a1.w = fmaf(gv, w1v.w, a1.w);           \
      a2.x = fmaf(gv, w2v.x, a2.x); a2.y = fmaf(gv, w2v.y, a2.y);           \
      a2.z = fmaf(gv, w2v.z, a2.z); a2.w = fmaf(gv, w2v.w, a2.w);           \
      a3.x = fmaf(gv, w3v.x, a3.x); a3.y = fmaf(gv, w3v.y, a3.y);           \
      a3.z = fmaf(gv, w3v.z, a3.z); a3.w = fmaf(gv, w3v.w, a3.w);           \
    }
    for (int c = 0; c < 64; c += 4) {
      float4 g4 = *(const float4*)(Ak + c);
      FMA16(g4.x, wT2 + (c + 0) * 128 + t0);
      FMA16(g4.y, wT2 + (c + 1) * 128 + t0);
      FMA16(g4.z, wT2 + (c + 2) * 128 + t0);
      FMA16(g4.w, wT2 + (c + 3) * 128 + t0);
    }
    float* o = &Cf[k * 132 + t0];
    *(float4*)(o + 0) = a0;
    *(float4*)(o + 4) = a1;
    *(float4*)(o + 8) = a2;
    *(float4*)(o + 12) = a3;
  }
  __syncthreads();
  // ---- max over k, relu, store
  if (tid < 128) {
    float m = Cf[tid];
    for (int kk = 1; kk < 32; ++kk) m = fmaxf(m, Cf[kk * 132 + tid]);
    out[(size_t)(NB * NS * 3) + (size_t)q * 128 + tid] = fmaxf(m, 0.0f);
  }
}

extern "C" void kernel_launch(void* const* d_in, const int* in_sizes, int n_in,
                              void* d_out, int out_size, void* d_ws, size_t ws_size,
                              hipStream_t stream)
{
  (void)in_sizes; (void)n_in; (void)out_size; (void)ws_size;
  const float* xyz  = (const float*)d_in[0];
  const float* feat = (const float*)d_in[1];
  const float* w0 = (const float*)d_in[2];
  const float* b0 = (const float*)d_in[3];
  const float* g0 = (const float*)d_in[4];
  const float* be0 = (const float*)d_in[5];
  const float* m0 = (const float*)d_in[6];
  const float* v0 = (const float*)d_in[7];
  const float* w1 = (const float*)d_in[8];
  const float* b1 = (const float*)d_in[9];
  const float* g1 = (const float*)d_in[10];
  const float* be1 = (const float*)d_in[11];
  const float* m1 = (const float*)d_in[12];
  const float* v1 = (const float*)d_in[13];
  const float* w2 = (const float*)d_in[14];
  const float* b2 = (const float*)d_in[15];
  const float* g2 = (const float*)d_in[16];
  const float* be2 = (const float*)d_in[17];
  const float* m2 = (const float*)d_in[18];
  const float* v2 = (const float*)d_in[19];

  float* ws = (float*)d_ws;
  int* fpsi = (int*)(ws + WS_FPSIDX);
  float4* pack = (float4*)(ws + WS_PACK);
  int* gidx = (int*)(ws + WS_GIDX);
  float* wT0 = ws + WS_WT0; float* bb0 = ws + WS_BB0;
  float* wT1 = ws + WS_WT1; float* bb1 = ws + WS_BB1;
  float* wT2 = ws + WS_WT2; float* bb2 = ws + WS_BB2;
  float* nxyz = (float*)d_out;

  hipLaunchKernelGGL(prep_pack, dim3((NB * NN + 255) / 256), dim3(256), 0, stream,
                     xyz, pack);
  hipLaunchKernelGGL(prep_w, dim3(66), dim3(256), 0, stream,
                     w0, b0, g0, be0, m0, v0,
                     w1, b1, g1, be1, m1, v1,
                     w2, b2, g2, be2, m2, v2,
                     wT0, bb0, wT1, bb1, wT2, bb2);
  hipLaunchKernelGGL(fps_kernel, dim3(NB), dim3(1024), 0, stream,
                     xyz, fpsi, nxyz);
  hipLaunchKernelGGL(ballq_kernel, dim3(NB * NS / 4), dim3(256), 0, stream,
                     pack, fpsi, gidx);
  hipLaunchKernelGGL(mlp_kernel, dim3(NB * NS), dim3(256), 0, stream,
                     xyz, feat, gidx, nxyz,
                     wT0, bb0, wT1, bb1, wT2, bb2, (float*)d_out);
}

// Round 12
// 1926.307 us; speedup vs baseline: 1.4611x; 1.4298x over previous
//
#include <hip/hip_runtime.h>

#define NB 4
#define NN 8192
#define NS 2048
#define NK 32
#define NCF 64
#define R2 0.04f

// ws layout in float units
#define WS_FPSIDX 0              // int[NB*NS]           = 8192
#define WS_PACK   8192           // float4[NB*NN]        = 131072 floats
#define WS_GIDX   139264         // int[NB*NS*NK]        = 262144
#define WS_WT0    401408         // 67*64
#define WS_BB0    405696         // 64
#define WS_WT1    405760         // 64*64
#define WS_BB1    409856         // 64
#define WS_WT2    409920         // 64*128
#define WS_BB2    418112         // 128

__device__ __forceinline__ unsigned long long umax64(unsigned long long a,
                                                     unsigned long long b) {
  return a > b ? a : b;   // v_cmp_lt_u64 + cndmask pair
}

template <int CTRL>
__device__ __forceinline__ void dpp_max64(unsigned& kl, unsigned& kh) {
  // 64-bit max ladder step: bound_ctrl=true -> shifted-in lanes see key=0,
  // which never wins (real keys have kl = ~idx > 0).
  unsigned nl = (unsigned)__builtin_amdgcn_update_dpp(0, (int)kl, CTRL, 0xf, 0xf, true);
  unsigned nh = (unsigned)__builtin_amdgcn_update_dpp(0, (int)kh, CTRL, 0xf, 0xf, true);
  unsigned long long cur = ((unsigned long long)kh << 32) | kl;
  unsigned long long oth = ((unsigned long long)nh << 32) | nl;
  bool take = oth > cur;
  kl = take ? nl : kl;
  kh = take ? nh : kh;
}

template <int CTRL>
__device__ __forceinline__ float dpp_fmin2(float x) {
  // bound_ctrl=false + old=x: invalid lanes contribute x itself (idempotent).
  int t = __builtin_amdgcn_update_dpp(__float_as_int(x), __float_as_int(x),
                                      CTRL, 0xf, 0xf, false);
  return fminf(x, __int_as_float(t));
}
template <int CTRL>
__device__ __forceinline__ float dpp_fmax2(float x) {
  int t = __builtin_amdgcn_update_dpp(__float_as_int(x), __float_as_int(x),
                                      CTRL, 0xf, 0xf, false);
  return fmaxf(x, __int_as_float(t));
}
__device__ __forceinline__ float wave_min_bcast(float x) {
  x = dpp_fmin2<0x111>(x); x = dpp_fmin2<0x112>(x); x = dpp_fmin2<0x114>(x);
  x = dpp_fmin2<0x118>(x); x = dpp_fmin2<0x142>(x); x = dpp_fmin2<0x143>(x);
  return __int_as_float(__builtin_amdgcn_readlane(__float_as_int(x), 63));
}
__device__ __forceinline__ float wave_max_bcast(float x) {
  x = dpp_fmax2<0x111>(x); x = dpp_fmax2<0x112>(x); x = dpp_fmax2<0x114>(x);
  x = dpp_fmax2<0x118>(x); x = dpp_fmax2<0x142>(x); x = dpp_fmax2<0x143>(x);
  return __int_as_float(__builtin_amdgcn_readlane(__float_as_int(x), 63));
}

__device__ __forceinline__ int morton9(int ix, int iy, int iz) {
  // 3 bits each, interleaved: compact spatial runs of consecutive cell ids.
  auto sp = [](int v) { return (v & 1) | ((v & 2) << 2) | ((v & 4) << 4); };
  return sp(ix) | (sp(iy) << 1) | (sp(iz) << 2);
}

// ---------------------------------------------------------------------------
// FPS (R8-exact structure, best measured at 1610 us): one block per batch,
// 1024 threads (16 waves), 8 points/thread.
// Exact semantics preserved: dist init 1e10f, far0=0,
// d = ((dx*dx+dy*dy)+dz*dz) with NO fma contraction; dist=min(dist,d);
// argmax first-index tiebreak via u64 keys (distbits<<32 | ~idx).
// Morton-binned waves own spatially compact 512-pt runs with exact float
// register bboxes. A wave updates only if lb(bbox,c)^2 * 0.999 < cachedmax;
// otherwise the whole min() pass is provably a no-op and the cached key is
// republished -> bit-identical selection. Lesson from R10/R11: keep the
// full-update path lean (single tree + single ladder), test cost minimal.
// ---------------------------------------------------------------------------
__global__ __launch_bounds__(1024)
void fps_kernel(const float* __restrict__ xyz, int* __restrict__ fps_idx,
                float* __restrict__ new_xyz)
{
#pragma clang fp contract(off)
  const int b = blockIdx.x;
  const int tid = threadIdx.x;
  const int lane = tid & 63;
  const int wid = tid >> 6;
  const float* __restrict__ P = xyz + (size_t)b * (NN * 3);

  __shared__ float Pl[NN * 3];                 // 96 KB staged coords
  __shared__ unsigned short sidx[NN];          // 16 KB binned orig indices
  __shared__ int hist[512];                    // Morton-cell histogram/offsets
  __shared__ unsigned long long skey[2][16];   // double-buffered wave keys

  // ---- one-time: stage coords, Morton-bin, scatter ----
  {
    const float4* __restrict__ src = (const float4*)P;
    float4* dst = (float4*)Pl;
#pragma unroll
    for (int i = 0; i < 6; ++i) dst[tid + i * 1024] = src[tid + i * 1024];
  }
  if (tid < 512) hist[tid] = 0;
  __syncthreads();

  unsigned short mycell[8];
#pragma unroll
  for (int j = 0; j < 8; ++j) {
    int p = tid + j * 1024;
    float x = Pl[p * 3 + 0], y = Pl[p * 3 + 1], z = Pl[p * 3 + 2];
    int ix = min(7, max(0, (int)(x * 8.0f)));
    int iy = min(7, max(0, (int)(y * 8.0f)));
    int iz = min(7, max(0, (int)(z * 8.0f)));
    int cell = morton9(ix, iy, iz);
    mycell[j] = (unsigned short)cell;
    atomicAdd(&hist[cell], 1);
  }
  __syncthreads();
  if (tid == 0) {   // exclusive prefix (one-time; 512 cells)
    int acc = 0;
    for (int c = 0; c < 512; ++c) { int h = hist[c]; hist[c] = acc; acc += h; }
  }
  __syncthreads();
#pragma unroll
  for (int j = 0; j < 8; ++j) {
    int p = tid + j * 1024;
    int pos = atomicAdd(&hist[mycell[j]], 1);
    sidx[pos] = (unsigned short)p;
  }
  __syncthreads();

  // ---- load my 8 binned points + keys; wave slots are contiguous 512 ----
  float px[8], py[8], pz[8], dist[8];
  unsigned klc[8];
#pragma unroll
  for (int j = 0; j < 8; ++j) {
    int slot = wid * 512 + j * 64 + lane;
    int p = sidx[slot];
    px[j] = Pl[p * 3 + 0];
    py[j] = Pl[p * 3 + 1];
    pz[j] = Pl[p * 3 + 2];
    dist[j] = 1e10f;
    klc[j] = 0xFFFFFFFFu - (unsigned)p;   // ~orig idx: bigger == smaller index
  }
  // ---- wave bbox (registers, broadcast via readlane) ----
  float mnx = fminf(fminf(fminf(px[0], px[1]), fminf(px[2], px[3])),
                    fminf(fminf(px[4], px[5]), fminf(px[6], px[7])));
  float mxx = fmaxf(fmaxf(fmaxf(px[0], px[1]), fmaxf(px[2], px[3])),
                    fmaxf(fmaxf(px[4], px[5]), fmaxf(px[6], px[7])));
  float mny = fminf(fminf(fminf(py[0], py[1]), fminf(py[2], py[3])),
                    fminf(fminf(py[4], py[5]), fminf(py[6], py[7])));
  float mxy = fmaxf(fmaxf(fmaxf(py[0], py[1]), fmaxf(py[2], py[3])),
                    fmaxf(fmaxf(py[4], py[5]), fmaxf(py[6], py[7])));
  float mnz = fminf(fminf(fminf(pz[0], pz[1]), fminf(pz[2], pz[3])),
                    fminf(fminf(pz[4], pz[5]), fminf(pz[6], pz[7])));
  float mxz = fmaxf(fmaxf(fmaxf(pz[0], pz[1]), fmaxf(pz[2], pz[3])),
                    fmaxf(fmaxf(pz[4], pz[5]), fmaxf(pz[6], pz[7])));
  const float blx = wave_min_bcast(mnx), bhx = wave_max_bcast(mxx);
  const float bly = wave_min_bcast(mny), bhy = wave_max_bcast(mxy);
  const float blz = wave_min_bcast(mnz), bhz = wave_max_bcast(mxz);

  float cx = P[0], cy = P[1], cz = P[2];   // first center = point 0
  int far = 0;
  unsigned ckl = 0u, ckh = 0u;             // cached wave key (lane 63 holds it)
  float cachedmax = 1e10f;                 // forces update at k=0

  for (int k = 0; k < NS; ++k) {
    if (tid == 0) {
      fps_idx[b * NS + k] = far;
      float* o = new_xyz + ((size_t)b * NS + k) * 3;
      o[0] = cx; o[1] = cy; o[2] = cz;
    }
    if (k == NS - 1) break;

    // ---- bbox pruning test (wave-uniform; skip is provably a no-op) ----
    float dlx = fmaxf(fmaxf(blx - cx, cx - bhx), 0.0f);
    float dly = fmaxf(fmaxf(bly - cy, cy - bhy), 0.0f);
    float dlz = fmaxf(fmaxf(blz - cz, cz - bhz), 0.0f);
    float dlb = dlx * dlx + dly * dly + dlz * dlz;
    int doupd = __builtin_amdgcn_readfirstlane(
        (int)!(dlb * 0.999f >= cachedmax));
    if (doupd) {
      // ---- distance update (exact math) + u64 key build
      unsigned long long k8[8];
#pragma unroll
      for (int j = 0; j < 8; ++j) {
        float dx = px[j] - cx;
        float dy = py[j] - cy;
        float dz = pz[j] - cz;
        float d = (dx * dx + dy * dy) + dz * dz;   // plain mul/add, l-to-r
        float t = fminf(dist[j], d);
        dist[j] = t;
        k8[j] = ((unsigned long long)(unsigned)__float_as_int(t) << 32) | klc[j];
      }
      unsigned long long t0 = umax64(k8[0], k8[1]);
      unsigned long long t1 = umax64(k8[2], k8[3]);
      unsigned long long t2 = umax64(k8[4], k8[5]);
      unsigned long long t3 = umax64(k8[6], k8[7]);
      unsigned long long bk = umax64(umax64(t0, t1), umax64(t2, t3));

      unsigned kl = (unsigned)bk, kh = (unsigned)(bk >> 32);
      dpp_max64<0x111>(kl, kh);
      dpp_max64<0x112>(kl, kh);
      dpp_max64<0x114>(kl, kh);
      dpp_max64<0x118>(kl, kh);
      dpp_max64<0x142>(kl, kh);
      dpp_max64<0x143>(kl, kh);
      ckl = kl; ckh = kh;
      cachedmax = __int_as_float(__builtin_amdgcn_readlane((int)kh, 63));
    }

    const int ws = k & 1;
    if (lane == 63) {
      skey[ws][wid] = ((unsigned long long)ckh << 32) | ckl;
    }
    __syncthreads();

    // ---- cross-wave reduce over 16 u64 keys (conflict-free b64 reads)
    unsigned long long sk = skey[ws][lane & 15];
    unsigned skl = (unsigned)sk, skh = (unsigned)(sk >> 32);
    dpp_max64<0x111>(skl, skh);
    dpp_max64<0x112>(skl, skh);
    dpp_max64<0x114>(skl, skh);
    dpp_max64<0x118>(skl, skh);  // lane15 of each row = block max
    unsigned kl15 = (unsigned)__builtin_amdgcn_readlane((int)skl, 15);
    far = (int)(0xFFFFFFFFu - kl15);

    // ---- center coords: one same-address broadcast LDS read (all waves)
    const float* cp = Pl + far * 3;
    cx = cp[0]; cy = cp[1]; cz = cp[2];
  }
}

// ---------------------------------------------------------------------------
// pack = {x, y, z, (x*x+y*y)+z*z} per point (sq matches jnp.sum(xyz**2,-1))
// ---------------------------------------------------------------------------
__global__ void prep_pack(const float* __restrict__ xyz, float4* __restrict__ pack)
{
#pragma clang fp contract(off)
  int t = blockIdx.x * 256 + threadIdx.x;
  if (t < NB * NN) {
    float x = xyz[t * 3 + 0], y = xyz[t * 3 + 1], z = xyz[t * 3 + 2];
    float4 v; v.x = x; v.y = y; v.z = z; v.w = (x * x + y * y) + z * z;
    pack[t] = v;
  }
}

// ---------------------------------------------------------------------------
// Fold BN into weights, transpose to (c,o), remap layer0 channels so that
// c'=0..63 are features (orig 3..66) and c'=64..66 are rel-xyz (orig 0..2).
// ---------------------------------------------------------------------------
__global__ void prep_w(
    const float* __restrict__ w0, const float* __restrict__ b0,
    const float* __restrict__ g0, const float* __restrict__ be0,
    const float* __restrict__ m0, const float* __restrict__ v0,
    const float* __restrict__ w1, const float* __restrict__ b1,
    const float* __restrict__ g1, const float* __restrict__ be1,
    const float* __restrict__ m1, const float* __restrict__ v1,
    const float* __restrict__ w2, const float* __restrict__ b2,
    const float* __restrict__ g2, const float* __restrict__ be2,
    const float* __restrict__ m2, const float* __restrict__ v2,
    float* __restrict__ wT0, float* __restrict__ bb0,
    float* __restrict__ wT1, float* __restrict__ bb1,
    float* __restrict__ wT2, float* __restrict__ bb2)
{
  int t = blockIdx.x * 256 + threadIdx.x;
  if (t < 4288) {
    int c = t >> 6, o = t & 63;
    int oc = (c < 64) ? (c + 3) : (c - 64);
    float sc = g0[o] * rsqrtf(v0[o] + 1e-5f);
    wT0[t] = w0[o * 67 + oc] * sc;
  } else if (t < 4352) {
    int o = t - 4288;
    float sc = g0[o] * rsqrtf(v0[o] + 1e-5f);
    bb0[o] = (b0[o] - m0[o]) * sc + be0[o];
  } else if (t < 8448) {
    int u = t - 4352;
    int c = u >> 6, o = u & 63;
    float sc = g1[o] * rsqrtf(v1[o] + 1e-5f);
    wT1[u] = w1[o * 64 + c] * sc;
  } else if (t < 8512) {
    int o = t - 8448;
    float sc = g1[o] * rsqrtf(v1[o] + 1e-5f);
    bb1[o] = (b1[o] - m1[o]) * sc + be1[o];
  } else if (t < 16704) {
    int u = t - 8512;
    int c = u >> 7, o = u & 127;
    float sc = g2[o] * rsqrtf(v2[o] + 1e-5f);
    wT2[u] = w2[o * 64 + c] * sc;
  } else if (t < 16832) {
    int o = t - 16704;
    float sc = g2[o] * rsqrtf(v2[o] + 1e-5f);
    bb2[o] = (b2[o] - m2[o]) * sc + be2[o];
  }
}

// ---------------------------------------------------------------------------
// Ball query: one wave per query point. sqr = (sq_q + sq_x) - 2*dot with
// dot as Eigen-style fma chain over (x,y,z). Packed {x,y,z,sq} float4 loads
// (1 dwordx4/point). First 32 in-ball indices ascending; pad with first hit.
// ---------------------------------------------------------------------------
__global__ __launch_bounds__(256)
void ballq_kernel(const float4* __restrict__ pack,
                  const int* __restrict__ fps_idx, int* __restrict__ gidx)
{
#pragma clang fp contract(off)
  const int lane = threadIdx.x & 63;
  const int q = blockIdx.x * 4 + (threadIdx.x >> 6);
  const int b = q >> 11;
  const int s = q & 2047;
  const float4* __restrict__ PK = pack + (size_t)b * NN;
  const int cidx = fps_idx[b * NS + s];
  const float4 c4 = PK[cidx];
  const float cx = c4.x, cy = c4.y, cz = c4.z, csq = c4.w;
  int* __restrict__ g = gidx + (size_t)q * NK;
  int cnt = 0, firstn = 0;
  bool havefirst = false;
  for (int n0 = 0; n0 < NN; n0 += 64) {
    int n = n0 + lane;
    float4 p4 = PK[n];
    float dot = p4.x * cx;         // first gebp step: fma(a0,b0,0) == rn(a0*b0)
    dot = fmaf(p4.y, cy, dot);
    dot = fmaf(p4.z, cz, dot);
    float sqr = (csq + p4.w) - 2.0f * dot;
    bool in_ = (sqr <= R2);
    unsigned long long m = __ballot(in_);
    if (!havefirst && m) { firstn = n0 + __builtin_ctzll(m); havefirst = true; }
    int pos = cnt + __popcll(m & ((1ull << lane) - 1ull));
    if (in_ && pos < NK) g[pos] = n;
    cnt += __popcll(m);
    if (cnt >= NK) break;
  }
  if (cnt < NK && lane < NK - cnt) g[cnt + lane] = firstn;
}

// ---------------------------------------------------------------------------
// Grouped MLP + k-max: one block (256 thr) per query. Activations in LDS;
// NEW: each layer's folded weight matrix is cooperatively staged into one
// reused 32KB LDS buffer (load W -> bar -> layer -> bar -> next), removing
// the 32x-redundant per-thread global weight re-reads that thrashed L1.
// Same floats, same FMA order -> bit-identical output. ReLU of layer 3
// deferred past the max (relu(max) == max(relu)).
// ---------------------------------------------------------------------------
__global__ __launch_bounds__(256)
void mlp_kernel(const float* __restrict__ xyz, const float* __restrict__ feat,
                const int* __restrict__ gidx, const float* __restrict__ nxyz,
                const float* __restrict__ wT0, const float* __restrict__ bb0,
                const float* __restrict__ wT1, const float* __restrict__ bb1,
                const float* __restrict__ wT2, const float* __restrict__ bb2,
                float* __restrict__ out)
{
  const int q = blockIdx.x;
  const int b = q >> 11;
  const int tid = threadIdx.x;
  __shared__ int sg[32];
  __shared__ float A[32 * 76];    // stride 76 (=19*4): 16B-aligned rows
  __shared__ float Bf[32 * 76];
  __shared__ float Cf[32 * 132];
  __shared__ float Wb[8192];      // 32KB reused weight buffer (max 64*128)
  if (tid < 32) sg[tid] = gidx[(size_t)q * NK + tid];
  __syncthreads();
  const int k = tid >> 3, j = tid & 7;
  {
    const int p = sg[k];
    const float* fp = feat + ((size_t)b * NN + p) * NCF + j * 8;
    float4 f0 = *(const float4*)fp;
    float4 f1 = *(const float4*)(fp + 4);
    float* a = &A[k * 76 + j * 8];
    *(float4*)a = f0;
    *(float4*)(a + 4) = f1;
    if (j == 0) {
      float cx = nxyz[(size_t)q * 3 + 0];
      float cy = nxyz[(size_t)q * 3 + 1];
      float cz = nxyz[(size_t)q * 3 + 2];
      const float* pp = xyz + ((size_t)b * NN + p) * 3;
      A[k * 76 + 64] = pp[0] - cx;
      A[k * 76 + 65] = pp[1] - cy;
      A[k * 76 + 66] = pp[2] - cz;
    }
  }
  // ---- stage W0 (67*64 = 4288 floats = 1072 float4)
  {
    const float4* src = (const float4*)wT0;
    float4* dst = (float4*)Wb;
    for (int i = tid; i < 1072; i += 256) dst[i] = src[i];
  }
  __syncthreads();
  const int o0 = j * 8;
#define FMA8(gv, base)                                                      \
  {                                                                         \
    const float* wr = (base);                                               \
    float4 wa = *(const float4*)wr;                                         \
    float4 wb = *(const float4*)(wr + 4);                                   \
    a0.x = fmaf(gv, wa.x, a0.x); a0.y = fmaf(gv, wa.y, a0.y);               \
    a0.z = fmaf(gv, wa.z, a0.z); a0.w = fmaf(gv, wa.w, a0.w);               \
    a1.x = fmaf(gv, wb.x, a1.x); a1.y = fmaf(gv, wb.y, a1.y);               \
    a1.z = fmaf(gv, wb.z, a1.z); a1.w = fmaf(gv, wb.w, a1.w);               \
  }
  // ---- layer 1: A[k][0..66] x Wb -> Bf[k][0..63]
  {
    float4 a0 = *(const float4*)(bb0 + o0);
    float4 a1 = *(const float4*)(bb0 + o0 + 4);
    const float* Ak = &A[k * 76];
    for (int c = 0; c < 64; c += 4) {
      float4 g4 = *(const float4*)(Ak + c);
      FMA8(g4.x, Wb + (c + 0) * 64 + o0);
      FMA8(g4.y, Wb + (c + 1) * 64 + o0);
      FMA8(g4.z, Wb + (c + 2) * 64 + o0);
      FMA8(g4.w, Wb + (c + 3) * 64 + o0);
    }
    FMA8(Ak[64], Wb + 64 * 64 + o0);
    FMA8(Ak[65], Wb + 65 * 64 + o0);
    FMA8(Ak[66], Wb + 66 * 64 + o0);
    float* o = &Bf[k * 76 + o0];
    o[0] = fmaxf(a0.x, 0.f); o[1] = fmaxf(a0.y, 0.f);
    o[2] = fmaxf(a0.z, 0.f); o[3] = fmaxf(a0.w, 0.f);
    o[4] = fmaxf(a1.x, 0.f); o[5] = fmaxf(a1.y, 0.f);
    o[6] = fmaxf(a1.z, 0.f); o[7] = fmaxf(a1.w, 0.f);
  }
  __syncthreads();
  // ---- stage W1 (64*64 = 4096 floats = 1024 float4)
  {
    const float4* src = (const float4*)wT1;
    float4* dst = (float4*)Wb;
    for (int i = tid; i < 1024; i += 256) dst[i] = src[i];
  }
  __syncthreads();
  // ---- layer 2: Bf[k][0..63] x Wb -> A[k][0..63]
  {
    float4 a0 = *(const float4*)(bb1 + o0);
    float4 a1 = *(const float4*)(bb1 + o0 + 4);
    const float* Bk = &Bf[k * 76];
    for (int c = 0; c < 64; c += 4) {
      float4 g4 = *(const float4*)(Bk + c);
      FMA8(g4.x, Wb + (c + 0) * 64 + o0);
      FMA8(g4.y, Wb + (c + 1) * 64 + o0);
      FMA8(g4.z, Wb + (c + 2) * 64 + o0);
      FMA8(g4.w, Wb + (c + 3) * 64 + o0);
    }
    float* o = &A[k * 76 + o0];
    o[0] = fmaxf(a0.x, 0.f); o[1] = fmaxf(a0.y, 0.f);
    o[2] = fmaxf(a0.z, 0.f); o[3] = fmaxf(a0.w, 0.f);
    o[4] = fmaxf(a1.x, 0.f); o[5] = fmaxf(a1.y, 0.f);
    o[6] = fmaxf(a1.z, 0.f); o[7] = fmaxf(a1.w, 0.f);
  }
  __syncthreads();
  // ---- stage W2 (64*128 = 8192 floats = 2048 float4)
  {
    const float4* src = (const float4*)wT2;
    float4* dst = (float4*)Wb;
    for (int i = tid; i < 2048; i += 256) dst[i] = src[i];
  }
  __syncthreads();
  // ---- layer 3: A[k][0..63] x Wb -> Cf[k][0..127]  (no relu; folded into max)
  {
    const int t0 = j * 16;
    float4 a0 = *(const float4*)(bb2 + t0);
    float4 a1 = *(const float4*)(bb2 + t0 + 4);
    float4 a2 = *(const float4*)(bb2 + t0 + 8);
    float4 a3 = *(const float4*)(bb2 + t0 + 12);
    const float* Ak = &A[k * 76];
#define FMA16(gv, base)                                                     \
    {                                                                       \
      const float* wr = (base);                                             \
      float4 w0v = *(const float4*)wr;                                      \
      float4 w1v = *(const float4*)(wr + 4);                                \
      float4 w2v = *(const float4*)(wr + 8);                                \
      float4 w3v = *(const float4*)(wr + 12);                               \
      a0.x = fmaf(gv, w0v.x, a0.x); a0.y = fmaf(gv, w0v.y, a0.y);           \
      a0.z = fmaf(gv, w0v.z, a0.z); a0.w = fmaf(gv, w0v.w, a0.w);           \
      a1.x = fmaf(gv, w1v.x, a1.x); a1.y = fmaf(gv, w1v.y, a1.y);           \
      a1.z = fmaf(gv, w1v.z, a1.z); a1.w = fmaf(gv, w1v.w, a1.w);           \
      a2.x = fmaf(gv, w2v.x, a2.x); a2.y = fmaf(gv, w2v.y, a2.y);           \
      a2.z = fmaf(gv, w2v.z, a2.z); a2.w = fmaf(gv, w2v.w, a2.w);           \
      a3.x = fmaf(gv, w3v.x, a3.x); a3.y = fmaf(gv, w3v.y, a3.y);           \
      a3.z = fmaf(gv, w3v.z, a3.z); a3.w = fmaf(gv, w3v.w, a3.w);           \
    }
    for (int c = 0; c < 64; c += 4) {
      float4 g4 = *(const float4*)(Ak + c);
      FMA16(g4.x, Wb + (c + 0) * 128 + t0);
      FMA16(g4.y, Wb + (c + 1) * 128 + t0);
      FMA16(g4.z, Wb + (c + 2) * 128 + t0);
      FMA16(g4.w, Wb + (c + 3) * 128 + t0);
    }
    float* o = &Cf[k * 132 + t0];
    *(float4*)(o + 0) = a0;
    *(float4*)(o + 4) = a1;
    *(float4*)(o + 8) = a2;
    *(float4*)(o + 12) = a3;
  }
  __syncthreads();
  // ---- max over k, relu, store
  if (tid < 128) {
    float m = Cf[tid];
    for (int kk = 1; kk < 32; ++kk) m = fmaxf(m, Cf[kk * 132 + tid]);
    out[(size_t)(NB * NS * 3) + (size_t)q * 128 + tid] = fmaxf(m, 0.0f);
  }
}

extern "C" void kernel_launch(void* const* d_in, const int* in_sizes, int n_in,
                              void* d_out, int out_size, void* d_ws, size_t ws_size,
                              hipStream_t stream)
{
  (void)in_sizes; (void)n_in; (void)out_size; (void)ws_size;
  const float* xyz  = (const float*)d_in[0];
  const float* feat = (const float*)d_in[1];
  const float* w0 = (const float*)d_in[2];
  const float* b0 = (const float*)d_in[3];
  const float* g0 = (const float*)d_in[4];
  const float* be0 = (const float*)d_in[5];
  const float* m0 = (const float*)d_in[6];
  const float* v0 = (const float*)d_in[7];
  const float* w1 = (const float*)d_in[8];
  const float* b1 = (const float*)d_in[9];
  const float* g1 = (const float*)d_in[10];
  const float* be1 = (const float*)d_in[11];
  const float* m1 = (const float*)d_in[12];
  const float* v1 = (const float*)d_in[13];
  const float* w2 = (const float*)d_in[14];
  const float* b2 = (const float*)d_in[15];
  const float* g2 = (const float*)d_in[16];
  const float* be2 = (const float*)d_in[17];
  const float* m2 = (const float*)d_in[18];
  const float* v2 = (const float*)d_in[19];

  float* ws = (float*)d_ws;
  int* fpsi = (int*)(ws + WS_FPSIDX);
  float4* pack = (float4*)(ws + WS_PACK);
  int* gidx = (int*)(ws + WS_GIDX);
  float* wT0 = ws + WS_WT0; float* bb0 = ws + WS_BB0;
  float* wT1 = ws + WS_WT1; float* bb1 = ws + WS_BB1;
  float* wT2 = ws + WS_WT2; float* bb2 = ws + WS_BB2;
  float* nxyz = (float*)d_out;

  hipLaunchKernelGGL(prep_pack, dim3((NB * NN + 255) / 256), dim3(256), 0, stream,
                     xyz, pack);
  hipLaunchKernelGGL(prep_w, dim3(66), dim3(256), 0, stream,
                     w0, b0, g0, be0, m0, v0,
                     w1, b1, g1, be1, m1, v1,
                     w2, b2, g2, be2, m2, v2,
                     wT0, bb0, wT1, bb1, wT2, bb2);
  hipLaunchKernelGGL(fps_kernel, dim3(NB), dim3(1024), 0, stream,
                     xyz, fpsi, nxyz);
  hipLaunchKernelGGL(ballq_kernel, dim3(NB * NS / 4), dim3(256), 0, stream,
                     pack, fpsi, gidx);
  hipLaunchKernelGGL(mlp_kernel, dim3(NB * NS), dim3(256), 0, stream,
                     xyz, feat, gidx, nxyz,
                     wT0, bb0, wT1, bb1, wT2, bb2, (float*)d_out);
}

// Round 13
// 1902.988 us; speedup vs baseline: 1.4790x; 1.0123x over previous
//
#include <hip/hip_runtime.h>

#define NB 4
#define NN 8192
#define NS 2048
#define NK 32
#define NCF 64
#define R2 0.04f

// ws layout in float units
#define WS_FPSIDX 0              // int[NB*NS]           = 8192
#define WS_PACK   8192           // float4[NB*NN]        = 131072 floats
#define WS_GIDX   139264         // int[NB*NS*NK]        = 262144
#define WS_WT0    401408         // 67*64
#define WS_BB0    405696         // 64
#define WS_WT1    405760         // 64*64
#define WS_BB1    409856         // 64
#define WS_WT2    409920         // 64*128
#define WS_BB2    418112         // 128

__device__ __forceinline__ unsigned long long umax64(unsigned long long a,
                                                     unsigned long long b) {
  return a > b ? a : b;   // v_cmp_lt_u64 + cndmask pair
}

template <int CTRL>
__device__ __forceinline__ void dpp_max64(unsigned& kl, unsigned& kh) {
  // 64-bit max ladder step: bound_ctrl=true -> shifted-in lanes see key=0,
  // which never wins (real keys have kl = ~idx > 0).
  unsigned nl = (unsigned)__builtin_amdgcn_update_dpp(0, (int)kl, CTRL, 0xf, 0xf, true);
  unsigned nh = (unsigned)__builtin_amdgcn_update_dpp(0, (int)kh, CTRL, 0xf, 0xf, true);
  unsigned long long cur = ((unsigned long long)kh << 32) | kl;
  unsigned long long oth = ((unsigned long long)nh << 32) | nl;
  bool take = oth > cur;
  kl = take ? nl : kl;
  kh = take ? nh : kh;
}

template <int CTRL>
__device__ __forceinline__ float dpp_fmin2(float x) {
  // bound_ctrl=false + old=x: invalid lanes contribute x itself (idempotent).
  int t = __builtin_amdgcn_update_dpp(__float_as_int(x), __float_as_int(x),
                                      CTRL, 0xf, 0xf, false);
  return fminf(x, __int_as_float(t));
}
template <int CTRL>
__device__ __forceinline__ float dpp_fmax2(float x) {
  int t = __builtin_amdgcn_update_dpp(__float_as_int(x), __float_as_int(x),
                                      CTRL, 0xf, 0xf, false);
  return fmaxf(x, __int_as_float(t));
}
__device__ __forceinline__ float wave_min_bcast(float x) {
  x = dpp_fmin2<0x111>(x); x = dpp_fmin2<0x112>(x); x = dpp_fmin2<0x114>(x);
  x = dpp_fmin2<0x118>(x); x = dpp_fmin2<0x142>(x); x = dpp_fmin2<0x143>(x);
  return __int_as_float(__builtin_amdgcn_readlane(__float_as_int(x), 63));
}
__device__ __forceinline__ float wave_max_bcast(float x) {
  x = dpp_fmax2<0x111>(x); x = dpp_fmax2<0x112>(x); x = dpp_fmax2<0x114>(x);
  x = dpp_fmax2<0x118>(x); x = dpp_fmax2<0x142>(x); x = dpp_fmax2<0x143>(x);
  return __int_as_float(__builtin_amdgcn_readlane(__float_as_int(x), 63));
}

__device__ __forceinline__ int morton12(int ix, int iy, int iz) {
  // 4 bits each (16^3 grid), interleaved: bit k -> bit 3k.
  auto sp = [](int v) {
    return (v & 1) | ((v & 2) << 2) | ((v & 4) << 4) | ((v & 8) << 6);
  };
  return sp(ix) | (sp(iy) << 1) | (sp(iz) << 2);
}

// ---------------------------------------------------------------------------
// FPS (R8/R12 steady-state structure, UNCHANGED in the loop): one block per
// batch, 1024 threads (16 waves), 8 points/thread.
// Exact semantics preserved: dist init 1e10f, far0=0,
// d = ((dx*dx+dy*dy)+dz*dz) with NO fma contraction; dist=min(dist,d);
// argmax first-index tiebreak via u64 keys (distbits<<32 | ~idx).
// R13 change: Morton binning refined 8^3 -> 16^3 (4096 cells) so each
// wave's 512-pt run aligns to ~8x8x4 fine-cell dyadic blocks with 1/16-cell
// boundary spill -> much tighter wave bboxes -> fewer waves fail the
// (zero-cost) skip test per iteration. Selection output provably identical:
// binning is a permutation, keys carry original indices, bbox is computed
// from the actual owned points.
// ---------------------------------------------------------------------------
__global__ __launch_bounds__(1024)
void fps_kernel(const float* __restrict__ xyz, int* __restrict__ fps_idx,
                float* __restrict__ new_xyz)
{
#pragma clang fp contract(off)
  const int b = blockIdx.x;
  const int tid = threadIdx.x;
  const int lane = tid & 63;
  const int wid = tid >> 6;
  const float* __restrict__ P = xyz + (size_t)b * (NN * 3);

  __shared__ float Pl[NN * 3];                 // 96 KB staged coords
  __shared__ unsigned short sidx[NN];          // 16 KB binned orig indices
  __shared__ int hist[4096];                   // 16 KB fine-cell histogram
  __shared__ int hsum[64];                     // chunk partial sums (scan)
  __shared__ unsigned long long skey[2][16];   // double-buffered wave keys

  // ---- one-time: stage coords, Morton-bin (16^3), scatter ----
  {
    const float4* __restrict__ src = (const float4*)P;
    float4* dst = (float4*)Pl;
#pragma unroll
    for (int i = 0; i < 6; ++i) dst[tid + i * 1024] = src[tid + i * 1024];
  }
#pragma unroll
  for (int i = 0; i < 4; ++i) hist[tid + i * 1024] = 0;
  __syncthreads();

  unsigned short mycell[8];
#pragma unroll
  for (int j = 0; j < 8; ++j) {
    int p = tid + j * 1024;
    float x = Pl[p * 3 + 0], y = Pl[p * 3 + 1], z = Pl[p * 3 + 2];
    int ix = min(15, max(0, (int)(x * 16.0f)));
    int iy = min(15, max(0, (int)(y * 16.0f)));
    int iz = min(15, max(0, (int)(z * 16.0f)));
    int cell = morton12(ix, iy, iz);
    mycell[j] = (unsigned short)cell;
    atomicAdd(&hist[cell], 1);
  }
  __syncthreads();
  // ---- 3-phase exclusive prefix over 4096 cells (one-time) ----
  if (tid < 64) {      // phase A: local scan within 64-cell chunk
    int acc = 0;
    for (int c = 0; c < 64; ++c) {
      int h = hist[tid * 64 + c];
      hist[tid * 64 + c] = acc;
      acc += h;
    }
    hsum[tid] = acc;
  }
  __syncthreads();
  if (tid == 0) {      // phase B: scan the 64 chunk totals
    int acc = 0;
    for (int c = 0; c < 64; ++c) { int h = hsum[c]; hsum[c] = acc; acc += h; }
  }
  __syncthreads();
#pragma unroll
  for (int i = 0; i < 4; ++i) {  // phase C: add chunk offsets
    int c = tid + i * 1024;
    hist[c] += hsum[c >> 6];
  }
  __syncthreads();
#pragma unroll
  for (int j = 0; j < 8; ++j) {
    int p = tid + j * 1024;
    int pos = atomicAdd(&hist[mycell[j]], 1);
    sidx[pos] = (unsigned short)p;
  }
  __syncthreads();

  // ---- load my 8 binned points + keys; wave slots are contiguous 512 ----
  float px[8], py[8], pz[8], dist[8];
  unsigned klc[8];
#pragma unroll
  for (int j = 0; j < 8; ++j) {
    int slot = wid * 512 + j * 64 + lane;
    int p = sidx[slot];
    px[j] = Pl[p * 3 + 0];
    py[j] = Pl[p * 3 + 1];
    pz[j] = Pl[p * 3 + 2];
    dist[j] = 1e10f;
    klc[j] = 0xFFFFFFFFu - (unsigned)p;   // ~orig idx: bigger == smaller index
  }
  // ---- wave bbox (registers, broadcast via readlane) ----
  float mnx = fminf(fminf(fminf(px[0], px[1]), fminf(px[2], px[3])),
                    fminf(fminf(px[4], px[5]), fminf(px[6], px[7])));
  float mxx = fmaxf(fmaxf(fmaxf(px[0], px[1]), fmaxf(px[2], px[3])),
                    fmaxf(fmaxf(px[4], px[5]), fmaxf(px[6], px[7])));
  float mny = fminf(fminf(fminf(py[0], py[1]), fminf(py[2], py[3])),
                    fminf(fminf(py[4], py[5]), fminf(py[6], py[7])));
  float mxy = fmaxf(fmaxf(fmaxf(py[0], py[1]), fmaxf(py[2], py[3])),
                    fmaxf(fmaxf(py[4], py[5]), fmaxf(py[6], py[7])));
  float mnz = fminf(fminf(fminf(pz[0], pz[1]), fminf(pz[2], pz[3])),
                    fminf(fminf(pz[4], pz[5]), fminf(pz[6], pz[7])));
  float mxz = fmaxf(fmaxf(fmaxf(pz[0], pz[1]), fmaxf(pz[2], pz[3])),
                    fmaxf(fmaxf(pz[4], pz[5]), fmaxf(pz[6], pz[7])));
  const float blx = wave_min_bcast(mnx), bhx = wave_max_bcast(mxx);
  const float bly = wave_min_bcast(mny), bhy = wave_max_bcast(mxy);
  const float blz = wave_min_bcast(mnz), bhz = wave_max_bcast(mxz);

  float cx = P[0], cy = P[1], cz = P[2];   // first center = point 0
  int far = 0;
  unsigned ckl = 0u, ckh = 0u;             // cached wave key (lane 63 holds it)
  float cachedmax = 1e10f;                 // forces update at k=0

  for (int k = 0; k < NS; ++k) {
    if (tid == 0) {
      fps_idx[b * NS + k] = far;
      float* o = new_xyz + ((size_t)b * NS + k) * 3;
      o[0] = cx; o[1] = cy; o[2] = cz;
    }
    if (k == NS - 1) break;

    // ---- bbox pruning test (wave-uniform; skip is provably a no-op) ----
    float dlx = fmaxf(fmaxf(blx - cx, cx - bhx), 0.0f);
    float dly = fmaxf(fmaxf(bly - cy, cy - bhy), 0.0f);
    float dlz = fmaxf(fmaxf(blz - cz, cz - bhz), 0.0f);
    float dlb = dlx * dlx + dly * dly + dlz * dlz;
    int doupd = __builtin_amdgcn_readfirstlane(
        (int)!(dlb * 0.999f >= cachedmax));
    if (doupd) {
      // ---- distance update (exact math) + u64 key build
      unsigned long long k8[8];
#pragma unroll
      for (int j = 0; j < 8; ++j) {
        float dx = px[j] - cx;
        float dy = py[j] - cy;
        float dz = pz[j] - cz;
        float d = (dx * dx + dy * dy) + dz * dz;   // plain mul/add, l-to-r
        float t = fminf(dist[j], d);
        dist[j] = t;
        k8[j] = ((unsigned long long)(unsigned)__float_as_int(t) << 32) | klc[j];
      }
      unsigned long long t0 = umax64(k8[0], k8[1]);
      unsigned long long t1 = umax64(k8[2], k8[3]);
      unsigned long long t2 = umax64(k8[4], k8[5]);
      unsigned long long t3 = umax64(k8[6], k8[7]);
      unsigned long long bk = umax64(umax64(t0, t1), umax64(t2, t3));

      unsigned kl = (unsigned)bk, kh = (unsigned)(bk >> 32);
      dpp_max64<0x111>(kl, kh);
      dpp_max64<0x112>(kl, kh);
      dpp_max64<0x114>(kl, kh);
      dpp_max64<0x118>(kl, kh);
      dpp_max64<0x142>(kl, kh);
      dpp_max64<0x143>(kl, kh);
      ckl = kl; ckh = kh;
      cachedmax = __int_as_float(__builtin_amdgcn_readlane((int)kh, 63));
    }

    const int ws = k & 1;
    if (lane == 63) {
      skey[ws][wid] = ((unsigned long long)ckh << 32) | ckl;
    }
    __syncthreads();

    // ---- cross-wave reduce over 16 u64 keys (conflict-free b64 reads)
    unsigned long long sk = skey[ws][lane & 15];
    unsigned skl = (unsigned)sk, skh = (unsigned)(sk >> 32);
    dpp_max64<0x111>(skl, skh);
    dpp_max64<0x112>(skl, skh);
    dpp_max64<0x114>(skl, skh);
    dpp_max64<0x118>(skl, skh);  // lane15 of each row = block max
    unsigned kl15 = (unsigned)__builtin_amdgcn_readlane((int)skl, 15);
    far = (int)(0xFFFFFFFFu - kl15);

    // ---- center coords: one same-address broadcast LDS read (all waves)
    const float* cp = Pl + far * 3;
    cx = cp[0]; cy = cp[1]; cz = cp[2];
  }
}

// ---------------------------------------------------------------------------
// pack = {x, y, z, (x*x+y*y)+z*z} per point (sq matches jnp.sum(xyz**2,-1))
// ---------------------------------------------------------------------------
__global__ void prep_pack(const float* __restrict__ xyz, float4* __restrict__ pack)
{
#pragma clang fp contract(off)
  int t = blockIdx.x * 256 + threadIdx.x;
  if (t < NB * NN) {
    float x = xyz[t * 3 + 0], y = xyz[t * 3 + 1], z = xyz[t * 3 + 2];
    float4 v; v.x = x; v.y = y; v.z = z; v.w = (x * x + y * y) + z * z;
    pack[t] = v;
  }
}

// ---------------------------------------------------------------------------
// Fold BN into weights, transpose to (c,o), remap layer0 channels so that
// c'=0..63 are features (orig 3..66) and c'=64..66 are rel-xyz (orig 0..2).
// ---------------------------------------------------------------------------
__global__ void prep_w(
    const float* __restrict__ w0, const float* __restrict__ b0,
    const float* __restrict__ g0, const float* __restrict__ be0,
    const float* __restrict__ m0, const float* __restrict__ v0,
    const float* __restrict__ w1, const float* __restrict__ b1,
    const float* __restrict__ g1, const float* __restrict__ be1,
    const float* __restrict__ m1, const float* __restrict__ v1,
    const float* __restrict__ w2, const float* __restrict__ b2,
    const float* __restrict__ g2, const float* __restrict__ be2,
    const float* __restrict__ m2, const float* __restrict__ v2,
    float* __restrict__ wT0, float* __restrict__ bb0,
    float* __restrict__ wT1, float* __restrict__ bb1,
    float* __restrict__ wT2, float* __restrict__ bb2)
{
  int t = blockIdx.x * 256 + threadIdx.x;
  if (t < 4288) {
    int c = t >> 6, o = t & 63;
    int oc = (c < 64) ? (c + 3) : (c - 64);
    float sc = g0[o] * rsqrtf(v0[o] + 1e-5f);
    wT0[t] = w0[o * 67 + oc] * sc;
  } else if (t < 4352) {
    int o = t - 4288;
    float sc = g0[o] * rsqrtf(v0[o] + 1e-5f);
    bb0[o] = (b0[o] - m0[o]) * sc + be0[o];
  } else if (t < 8448) {
    int u = t - 4352;
    int c = u >> 6, o = u & 63;
    float sc = g1[o] * rsqrtf(v1[o] + 1e-5f);
    wT1[u] = w1[o * 64 + c] * sc;
  } else if (t < 8512) {
    int o = t - 8448;
    float sc = g1[o] * rsqrtf(v1[o] + 1e-5f);
    bb1[o] = (b1[o] - m1[o]) * sc + be1[o];
  } else if (t < 16704) {
    int u = t - 8512;
    int c = u >> 7, o = u & 127;
    float sc = g2[o] * rsqrtf(v2[o] + 1e-5f);
    wT2[u] = w2[o * 64 + c] * sc;
  } else if (t < 16832) {
    int o = t - 16704;
    float sc = g2[o] * rsqrtf(v2[o] + 1e-5f);
    bb2[o] = (b2[o] - m2[o]) * sc + be2[o];
  }
}

// ---------------------------------------------------------------------------
// Ball query: one wave per query point. sqr = (sq_q + sq_x) - 2*dot with
// dot as Eigen-style fma chain over (x,y,z). Packed {x,y,z,sq} float4 loads
// (1 dwordx4/point). First 32 in-ball indices ascending; pad with first hit.
// ---------------------------------------------------------------------------
__global__ __launch_bounds__(256)
void ballq_kernel(const float4* __restrict__ pack,
                  const int* __restrict__ fps_idx, int* __restrict__ gidx)
{
#pragma clang fp contract(off)
  const int lane = threadIdx.x & 63;
  const int q = blockIdx.x * 4 + (threadIdx.x >> 6);
  const int b = q >> 11;
  const int s = q & 2047;
  const float4* __restrict__ PK = pack + (size_t)b * NN;
  const int cidx = fps_idx[b * NS + s];
  const float4 c4 = PK[cidx];
  const float cx = c4.x, cy = c4.y, cz = c4.z, csq = c4.w;
  int* __restrict__ g = gidx + (size_t)q * NK;
  int cnt = 0, firstn = 0;
  bool havefirst = false;
  for (int n0 = 0; n0 < NN; n0 += 64) {
    int n = n0 + lane;
    float4 p4 = PK[n];
    float dot = p4.x * cx;         // first gebp step: fma(a0,b0,0) == rn(a0*b0)
    dot = fmaf(p4.y, cy, dot);
    dot = fmaf(p4.z, cz, dot);
    float sqr = (csq + p4.w) - 2.0f * dot;
    bool in_ = (sqr <= R2);
    unsigned long long m = __ballot(in_);
    if (!havefirst && m) { firstn = n0 + __builtin_ctzll(m); havefirst = true; }
    int pos = cnt + __popcll(m & ((1ull << lane) - 1ull));
    if (in_ && pos < NK) g[pos] = n;
    cnt += __popcll(m);
    if (cnt >= NK) break;
  }
  if (cnt < NK && lane < NK - cnt) g[cnt + lane] = firstn;
}

// ---------------------------------------------------------------------------
// Grouped MLP + k-max: one block (256 thr) per query. Activations in LDS;
// each layer's folded weight matrix cooperatively staged into one reused
// 32KB LDS buffer (R12 win: removed 32x-redundant global weight re-reads).
// Same floats, same FMA order -> bit-identical output. ReLU of layer 3
// deferred past the max (relu(max) == max(relu)).
// ---------------------------------------------------------------------------
__global__ __launch_bounds__(256)
void mlp_kernel(const float* __restrict__ xyz, const float* __restrict__ feat,
                const int* __restrict__ gidx, const float* __restrict__ nxyz,
                const float* __restrict__ wT0, const float* __restrict__ bb0,
                const float* __restrict__ wT1, const float* __restrict__ bb1,
                const float* __restrict__ wT2, const float* __restrict__ bb2,
                float* __restrict__ out)
{
  const int q = blockIdx.x;
  const int b = q >> 11;
  const int tid = threadIdx.x;
  __shared__ int sg[32];
  __shared__ float A[32 * 76];    // stride 76 (=19*4): 16B-aligned rows
  __shared__ float Bf[32 * 76];
  __shared__ float Cf[32 * 132];
  __shared__ float Wb[8192];      // 32KB reused weight buffer (max 64*128)
  if (tid < 32) sg[tid] = gidx[(size_t)q * NK + tid];
  __syncthreads();
  const int k = tid >> 3, j = tid & 7;
  {
    const int p = sg[k];
    const float* fp = feat + ((size_t)b * NN + p) * NCF + j * 8;
    float4 f0 = *(const float4*)fp;
    float4 f1 = *(const float4*)(fp + 4);
    float* a = &A[k * 76 + j * 8];
    *(float4*)a = f0;
    *(float4*)(a + 4) = f1;
    if (j == 0) {
      float cx = nxyz[(size_t)q * 3 + 0];
      float cy = nxyz[(size_t)q * 3 + 1];
      float cz = nxyz[(size_t)q * 3 + 2];
      const float* pp = xyz + ((size_t)b * NN + p) * 3;
      A[k * 76 + 64] = pp[0] - cx;
      A[k * 76 + 65] = pp[1] - cy;
      A[k * 76 + 66] = pp[2] - cz;
    }
  }
  // ---- stage W0 (67*64 = 4288 floats = 1072 float4)
  {
    const float4* src = (const float4*)wT0;
    float4* dst = (float4*)Wb;
    for (int i = tid; i < 1072; i += 256) dst[i] = src[i];
  }
  __syncthreads();
  const int o0 = j * 8;
#define FMA8(gv, base)                                                      \
  {                                                                         \
    const float* wr = (base);                                               \
    float4 wa = *(const float4*)wr;                                         \
    float4 wb = *(const float4*)(wr + 4);                                   \
    a0.x = fmaf(gv, wa.x, a0.x); a0.y = fmaf(gv, wa.y, a0.y);               \
    a0.z = fmaf(gv, wa.z, a0.z); a0.w = fmaf(gv, wa.w, a0.w);               \
    a1.x = fmaf(gv, wb.x, a1.x); a1.y = fmaf(gv, wb.y, a1.y);               \
    a1.z = fmaf(gv, wb.z, a1.z); a1.w = fmaf(gv, wb.w, a1.w);               \
  }
  // ---- layer 1: A[k][0..66] x Wb -> Bf[k][0..63]
  {
    float4 a0 = *(const float4*)(bb0 + o0);
    float4 a1 = *(const float4*)(bb0 + o0 + 4);
    const float* Ak = &A[k * 76];
    for (int c = 0; c < 64; c += 4) {
      float4 g4 = *(const float4*)(Ak + c);
      FMA8(g4.x, Wb + (c + 0) * 64 + o0);
      FMA8(g4.y, Wb + (c + 1) * 64 + o0);
      FMA8(g4.z, Wb + (c + 2) * 64 + o0);
      FMA8(g4.w, Wb + (c + 3) * 64 + o0);
    }
    FMA8(Ak[64], Wb + 64 * 64 + o0);
    FMA8(Ak[65], Wb + 65 * 64 + o0);
    FMA8(Ak[66], Wb + 66 * 64 + o0);
    float* o = &Bf[k * 76 + o0];
    o[0] = fmaxf(a0.x, 0.f); o[1] = fmaxf(a0.y, 0.f);
    o[2] = fmaxf(a0.z, 0.f); o[3] = fmaxf(a0.w, 0.f);
    o[4] = fmaxf(a1.x, 0.f); o[5] = fmaxf(a1.y, 0.f);
    o[6] = fmaxf(a1.z, 0.f); o[7] = fmaxf(a1.w, 0.f);
  }
  __syncthreads();
  // ---- stage W1 (64*64 = 4096 floats = 1024 float4)
  {
    const float4* src = (const float4*)wT1;
    float4* dst = (float4*)Wb;
    for (int i = tid; i < 1024; i += 256) dst[i] = src[i];
  }
  __syncthreads();
  // ---- layer 2: Bf[k][0..63] x Wb -> A[k][0..63]
  {
    float4 a0 = *(const float4*)(bb1 + o0);
    float4 a1 = *(const float4*)(bb1 + o0 + 4);
    const float* Bk = &Bf[k * 76];
    for (int c = 0; c < 64; c += 4) {
      float4 g4 = *(const float4*)(Bk + c);
      FMA8(g4.x, Wb + (c + 0) * 64 + o0);
      FMA8(g4.y, Wb + (c + 1) * 64 + o0);
      FMA8(g4.z, Wb + (c + 2) * 64 + o0);
      FMA8(g4.w, Wb + (c + 3) * 64 + o0);
    }
    float* o = &A[k * 76 + o0];
    o[0] = fmaxf(a0.x, 0.f); o[1] = fmaxf(a0.y, 0.f);
    o[2] = fmaxf(a0.z, 0.f); o[3] = fmaxf(a0.w, 0.f);
    o[4] = fmaxf(a1.x, 0.f); o[5] = fmaxf(a1.y, 0.f);
    o[6] = fmaxf(a1.z, 0.f); o[7] = fmaxf(a1.w, 0.f);
  }
  __syncthreads();
  // ---- stage W2 (64*128 = 8192 floats = 2048 float4)
  {
    const float4* src = (const float4*)wT2;
    float4* dst = (float4*)Wb;
    for (int i = tid; i < 2048; i += 256) dst[i] = src[i];
  }
  __syncthreads();
  // ---- layer 3: A[k][0..63] x Wb -> Cf[k][0..127]  (no relu; folded into max)
  {
    const int t0 = j * 16;
    float4 a0 = *(const float4*)(bb2 + t0);
    float4 a1 = *(const float4*)(bb2 + t0 + 4);
    float4 a2 = *(const float4*)(bb2 + t0 + 8);
    float4 a3 = *(const float4*)(bb2 + t0 + 12);
    const float* Ak = &A[k * 76];
#define FMA16(gv, base)                                                     \
    {                                                                       \
      const float* wr = (base);                                             \
      float4 w0v = *(const float4*)wr;                                      \
      float4 w1v = *(const float4*)(wr + 4);                                \
      float4 w2v = *(const float4*)(wr + 8);                                \
      float4 w3v = *(const float4*)(wr + 12);                               \
      a0.x = fmaf(gv, w0v.x, a0.x); a0.y = fmaf(gv, w0v.y, a0.y);           \
      a0.z = fmaf(gv, w0v.z, a0.z); a0.w = fmaf(gv, w0v.w, a0.w);           \
      a1.x = fmaf(gv, w1v.x, a1.x); a1.y = fmaf(gv, w1v.y, a1.y);           \
      a1.z = fmaf(gv, w1v.z, a1.z); a1.w = fmaf(gv, w1v.w, a1.w);           \
      a2.x = fmaf(gv, w2v.x, a2.x); a2.y = fmaf(gv, w2v.y, a2.y);           \
      a2.z = fmaf(gv, w2v.z, a2.z); a2.w = fmaf(gv, w2v.w, a2.w);           \
      a3.x = fmaf(gv, w3v.x, a3.x); a3.y = fmaf(gv, w3v.y, a3.y);           \
      a3.z = fmaf(gv, w3v.z, a3.z); a3.w = fmaf(gv, w3v.w, a3.w);           \
    }
    for (int c = 0; c < 64; c += 4) {
      float4 g4 = *(const float4*)(Ak + c);
      FMA16(g4.x, Wb + (c + 0) * 128 + t0);
      FMA16(g4.y, Wb + (c + 1) * 128 + t0);
      FMA16(g4.z, Wb + (c + 2) * 128 + t0);
      FMA16(g4.w, Wb + (c + 3) * 128 + t0);
    }
    float* o = &Cf[k * 132 + t0];
    *(float4*)(o + 0) = a0;
    *(float4*)(o + 4) = a1;
    *(float4*)(o + 8) = a2;
    *(float4*)(o + 12) = a3;
  }
  __syncthreads();
  // ---- max over k, relu, store
  if (tid < 128) {
    float m = Cf[tid];
    for (int kk = 1; kk < 32; ++kk) m = fmaxf(m, Cf[kk * 132 + tid]);
    out[(size_t)(NB * NS * 3) + (size_t)q * 128 + tid] = fmaxf(m, 0.0f);
  }
}

extern "C" void kernel_launch(void* const* d_in, const int* in_sizes, int n_in,
                              void* d_out, int out_size, void* d_ws, size_t ws_size,
                              hipStream_t stream)
{
  (void)in_sizes; (void)n_in; (void)out_size; (void)ws_size;
  const float* xyz  = (const float*)d_in[0];
  const float* feat = (const float*)d_in[1];
  const float* w0 = (const float*)d_in[2];
  const float* b0 = (const float*)d_in[3];
  const float* g0 = (const float*)d_in[4];
  const float* be0 = (const float*)d_in[5];
  const float* m0 = (const float*)d_in[6];
  const float* v0 = (const float*)d_in[7];
  const float* w1 = (const float*)d_in[8];
  const float* b1 = (const float*)d_in[9];
  const float* g1 = (const float*)d_in[10];
  const float* be1 = (const float*)d_in[11];
  const float* m1 = (const float*)d_in[12];
  const float* v1 = (const float*)d_in[13];
  const float* w2 = (const float*)d_in[14];
  const float* b2 = (const float*)d_in[15];
  const float* g2 = (const float*)d_in[16];
  const float* be2 = (const float*)d_in[17];
  const float* m2 = (const float*)d_in[18];
  const float* v2 = (const float*)d_in[19];

  float* ws = (float*)d_ws;
  int* fpsi = (int*)(ws + WS_FPSIDX);
  float4* pack = (float4*)(ws + WS_PACK);
  int* gidx = (int*)(ws + WS_GIDX);
  float* wT0 = ws + WS_WT0; float* bb0 = ws + WS_BB0;
  float* wT1 = ws + WS_WT1; float* bb1 = ws + WS_BB1;
  float* wT2 = ws + WS_WT2; float* bb2 = ws + WS_BB2;
  float* nxyz = (float*)d_out;

  hipLaunchKernelGGL(prep_pack, dim3((NB * NN + 255) / 256), dim3(256), 0, stream,
                     xyz, pack);
  hipLaunchKernelGGL(prep_w, dim3(66), dim3(256), 0, stream,
                     w0, b0, g0, be0, m0, v0,
                     w1, b1, g1, be1, m1, v1,
                     w2, b2, g2, be2, m2, v2,
                     wT0, bb0, wT1, bb1, wT2, bb2);
  hipLaunchKernelGGL(fps_kernel, dim3(NB), dim3(1024), 0, stream,
                     xyz, fpsi, nxyz);
  hipLaunchKernelGGL(ballq_kernel, dim3(NB * NS / 4), dim3(256), 0, stream,
                     pack, fpsi, gidx);
  hipLaunchKernelGGL(mlp_kernel, dim3(NB * NS), dim3(256), 0, stream,
                     xyz, feat, gidx, nxyz,
                     wT0, bb0, wT1, bb1, wT2, bb2, (float*)d_out);
}